// Round 2
// baseline (20039.171 us; speedup 1.0000x reference)
//
#include <hip/hip_runtime.h>
#include <math.h>

// ============================ helpers ============================
__device__ __forceinline__ float sigf(float x) { return 1.f / (1.f + expf(-x)); }

#define SCALE_CLAMP 4.135166556742356f
#define IMG_SIZE 800.f

// ==================== weight transpose: [ko][ci][tap] -> [ci][tap][ko] ====================
__global__ __launch_bounds__(256) void wtrans_k(const float* __restrict__ cls_tw,
                                                const float* __restrict__ bbox_tw,
                                                float* __restrict__ wt)
{
  const size_t total = 8ull * 589824ull;
  for (size_t i = (size_t)blockIdx.x * 256 + threadIdx.x; i < total; i += (size_t)gridDim.x * 256) {
    unsigned tt = (unsigned)(i / 589824ull);
    unsigned r  = (unsigned)(i - (size_t)tt * 589824ull);
    unsigned ci = r / 2304u;
    unsigned r2 = r - ci * 2304u;
    unsigned tap = r2 >> 8;
    unsigned ko  = r2 & 255u;
    const float* src = (tt < 4) ? (cls_tw + (size_t)tt * 589824ull)
                                : (bbox_tw + (size_t)(tt - 4) * 589824ull);
    wt[i] = src[(size_t)ko * 2304u + (size_t)ci * 9u + tap];
  }
}

// ==================== direct 3x3 conv + bias + relu ====================
// Input: NCHW (layer 0, unpadded, from d_in) or padded NHWC [(H+2)(W+2)][256].
// Output: padded NHWC, interior only (borders pre-zeroed by memset).
// Tile: PC positions x 128 ko, 256 threads, per-thread PJ x 8 accum, cin chunks of 8.
template<int H, int W, int PC, int PJ, bool NCHW_IN>
__global__ __launch_bounds__(256) void conv3x3_k(const float* __restrict__ in,
                                                 const float* __restrict__ wt,
                                                 const float* __restrict__ bias,
                                                 float* __restrict__ out)
{
  static_assert(PC == 16 * PJ, "PC=16*PJ");
  constexpr int PW  = W + 2;
  constexpr int PHW = (H + 2) * (W + 2);
  constexpr int HW  = H * W;
  constexpr int SPAN = PC + 2 * ((PC + W - 2) / W) + 2 * W + 9;

  __shared__ float in_s[8][SPAN];
  __shared__ float w_s[8][9][144];  // swizzled ko rows (2-way max bank conflict)

  const int t   = threadIdx.x;
  const int n   = blockIdx.z;
  const int P0  = blockIdx.x * PC;
  const int ko0 = blockIdx.y * 128;
  const int pg  = t & 15, kg = t >> 4;
  const int kbase = kg * 8;
  const int swb   = kbase + ((kbase >> 5) << 2);

  int pbase;
  { int y0 = P0 / W, x0 = P0 - y0 * W; pbase = y0 * PW + x0; }

  // offj points at the TOP-LEFT tap of the 3x3 window for output (y,x):
  // padded(y+ty, x+tx) = input(y-1+ty, x-1+tx).  (Round-1 bug: was +PW+1 off.)
  int offj[PJ]; bool valj[PJ];
#pragma unroll
  for (int j = 0; j < PJ; ++j) {
    int p = P0 + pg * PJ + j;
    valj[j] = (p < HW);
    if (p >= HW) p = HW - 1;
    int y = p / W, x = p - y * W;
    offj[j] = y * PW + x - pbase;
  }

  float acc[PJ][8];
#pragma unroll
  for (int j = 0; j < PJ; ++j)
#pragma unroll
    for (int k = 0; k < 8; ++k) acc[j][k] = 0.f;

  const float* inN = NCHW_IN ? (in + (size_t)n * HW * 256)
                             : (in + (size_t)n * PHW * 256);

  for (int c0 = 0; c0 < 256; c0 += 8) {
    // ---- stage input halo ----
    if (NCHW_IN) {
      for (int q = t; q < SPAN; q += 256) {
        int pp = pbase + q;
        int py = pp / PW, px = pp - py * PW;
        bool ok = (py >= 1) && (py <= H) && (px >= 1) && (px <= W);
        int ps = (py - 1) * W + (px - 1);
#pragma unroll
        for (int ci = 0; ci < 8; ++ci)
          in_s[ci][q] = ok ? inN[(size_t)(c0 + ci) * HW + ps] : 0.f;
      }
    } else {
      for (int q = t; q < SPAN; q += 256) {
        int pp = pbase + q;
        float4 v0 = make_float4(0,0,0,0), v1 = make_float4(0,0,0,0);
        if (pp >= 0 && pp < PHW) {
          const float4* src = (const float4*)(inN + (size_t)pp * 256 + c0);
          v0 = src[0]; v1 = src[1];
        }
        in_s[0][q] = v0.x; in_s[1][q] = v0.y; in_s[2][q] = v0.z; in_s[3][q] = v0.w;
        in_s[4][q] = v1.x; in_s[5][q] = v1.y; in_s[6][q] = v1.z; in_s[7][q] = v1.w;
      }
    }
    // ---- stage weights: 8ci x 9tap x 128ko (float4, swizzled rows) ----
    for (int i4 = t; i4 < 2304; i4 += 256) {
      int ci = i4 / 288; int rem = i4 - ci * 288; int tap = rem >> 5; int k4 = rem & 31;
      float4 v = *(const float4*)(wt + ((size_t)(c0 + ci) * 9 + tap) * 256 + ko0 + k4 * 4);
      int ko = k4 * 4;
      int sw = ko + ((ko >> 5) << 2);
      *(float4*)&w_s[ci][tap][sw] = v;
    }
    __syncthreads();

#pragma unroll
    for (int ci = 0; ci < 8; ++ci) {
#pragma unroll
      for (int tap = 0; tap < 9; ++tap) {
        const int d = (tap / 3) * PW + (tap % 3);
        float4 wa = *(const float4*)&w_s[ci][tap][swb];
        float4 wb = *(const float4*)&w_s[ci][tap][swb + 4];
#pragma unroll
        for (int j = 0; j < PJ; ++j) {
          float a = in_s[ci][offj[j] + d];
          acc[j][0] = fmaf(a, wa.x, acc[j][0]);
          acc[j][1] = fmaf(a, wa.y, acc[j][1]);
          acc[j][2] = fmaf(a, wa.z, acc[j][2]);
          acc[j][3] = fmaf(a, wa.w, acc[j][3]);
          acc[j][4] = fmaf(a, wb.x, acc[j][4]);
          acc[j][5] = fmaf(a, wb.y, acc[j][5]);
          acc[j][6] = fmaf(a, wb.z, acc[j][6]);
          acc[j][7] = fmaf(a, wb.w, acc[j][7]);
        }
      }
    }
    __syncthreads();
  }

  // ---- epilogue: bias + relu, store padded NHWC interior ----
  const int koT = ko0 + kbase;
  float bv[8];
#pragma unroll
  for (int k = 0; k < 8; ++k) bv[k] = bias[koT + k];
  float* outN = out + (size_t)n * PHW * 256;
#pragma unroll
  for (int j = 0; j < PJ; ++j) {
    if (!valj[j]) continue;
    int p = P0 + pg * PJ + j;
    int y = p / W, x = p - y * W;
    size_t pp = (size_t)(y + 1) * PW + x + 1;
    float4 o0, o1;
    o0.x = fmaxf(acc[j][0] + bv[0], 0.f);
    o0.y = fmaxf(acc[j][1] + bv[1], 0.f);
    o0.z = fmaxf(acc[j][2] + bv[2], 0.f);
    o0.w = fmaxf(acc[j][3] + bv[3], 0.f);
    o1.x = fmaxf(acc[j][4] + bv[4], 0.f);
    o1.y = fmaxf(acc[j][5] + bv[5], 0.f);
    o1.z = fmaxf(acc[j][6] + bv[6], 0.f);
    o1.w = fmaxf(acc[j][7] + bv[7], 0.f);
    *(float4*)(outN + pp * 256 + koT)     = o0;
    *(float4*)(outN + pp * 256 + koT + 4) = o1;
  }
}

// ==================== cls head: 80-wide 1x1 conv + sigmoid -> score[n][p*80+c] ====================
__global__ __launch_bounds__(256) void cls_head_k(const float* __restrict__ act,
                                                  const float* __restrict__ wcls,
                                                  const float* __restrict__ bcls,
                                                  float* __restrict__ score,
                                                  int HW, int W, int PW, int PHW)
{
  __shared__ int   p2s[64];
  __shared__ float as_[64][69];
  __shared__ float ws_[64][84];
  const int t = threadIdx.x;
  const int n = blockIdx.y;
  const int P0 = blockIdx.x * 64;
  if (t < 64) {
    int p = P0 + t; if (p >= HW) p = HW - 1;
    int y = p / W, x = p - y * W;
    p2s[t] = (y + 1) * PW + x + 1;
  }
  __syncthreads();
  float acc[4][5];
#pragma unroll
  for (int i = 0; i < 4; ++i)
#pragma unroll
    for (int j = 0; j < 5; ++j) acc[i][j] = 0.f;

  const float* actN = act + (size_t)n * PHW * 256;
  const int pg = t >> 4, cg = t & 15;

  for (int c0 = 0; c0 < 256; c0 += 64) {
    for (int i = t; i < 1024; i += 256) {
      int pos = i >> 4, c4 = i & 15;
      float4 v = *(const float4*)(actN + (size_t)p2s[pos] * 256 + c0 + c4 * 4);
      float* dst = &as_[pos][c4 * 4];
      dst[0] = v.x; dst[1] = v.y; dst[2] = v.z; dst[3] = v.w;
    }
    for (int i = t; i < 1280; i += 256) {
      int c = i >> 4, c4 = i & 15;
      float4 v = *(const float4*)(wcls + (size_t)c * 256 + c0 + c4 * 4);
      ws_[c4 * 4 + 0][c] = v.x; ws_[c4 * 4 + 1][c] = v.y;
      ws_[c4 * 4 + 2][c] = v.z; ws_[c4 * 4 + 3][c] = v.w;
    }
    __syncthreads();
#pragma unroll 8
    for (int ci = 0; ci < 64; ++ci) {
#pragma unroll
      for (int i = 0; i < 4; ++i) {
        float a = as_[pg * 4 + i][ci];
#pragma unroll
        for (int j = 0; j < 5; ++j)
          acc[i][j] = fmaf(a, ws_[ci][cg * 5 + j], acc[i][j]);
      }
    }
    __syncthreads();
  }
#pragma unroll
  for (int i = 0; i < 4; ++i) {
    int p = P0 + pg * 4 + i;
    if (p >= HW) continue;
#pragma unroll
    for (int j = 0; j < 5; ++j) {
      int c = cg * 5 + j;
      float lg = acc[i][j] + bcls[c];
      score[(size_t)n * HW * 80 + (size_t)p * 80 + c] = sigf(lg);
    }
  }
}

// ==================== box head: deltas (scaled) + centerness; score *= sig(ctr), threshold ====================
__global__ __launch_bounds__(256) void box_head_k(const float* __restrict__ act,
                                                  const float* __restrict__ wbox,
                                                  const float* __restrict__ bb,
                                                  const float* __restrict__ wctr,
                                                  const float* __restrict__ bc,
                                                  const float* __restrict__ scales, int level,
                                                  float* __restrict__ score,
                                                  float* __restrict__ deltas,
                                                  int HW, int W, int PW, int PHW)
{
  int n = blockIdx.y;
  int p = blockIdx.x * 256 + threadIdx.x;
  if (p >= HW) return;
  int y = p / W, x = p - y * W;
  const float* a = act + ((size_t)n * PHW + (size_t)(y + 1) * PW + x + 1) * 256;
  float d0 = 0, d1 = 0, d2 = 0, d3 = 0, ct = 0;
  for (int i = 0; i < 64; ++i) {
    float4 av = ((const float4*)a)[i];
    float4 w0 = ((const float4*)wbox)[0 * 64 + i];
    float4 w1 = ((const float4*)wbox)[1 * 64 + i];
    float4 w2 = ((const float4*)wbox)[2 * 64 + i];
    float4 w3 = ((const float4*)wbox)[3 * 64 + i];
    float4 wc = ((const float4*)wctr)[i];
    d0 = fmaf(av.x, w0.x, d0); d0 = fmaf(av.y, w0.y, d0); d0 = fmaf(av.z, w0.z, d0); d0 = fmaf(av.w, w0.w, d0);
    d1 = fmaf(av.x, w1.x, d1); d1 = fmaf(av.y, w1.y, d1); d1 = fmaf(av.z, w1.z, d1); d1 = fmaf(av.w, w1.w, d1);
    d2 = fmaf(av.x, w2.x, d2); d2 = fmaf(av.y, w2.y, d2); d2 = fmaf(av.z, w2.z, d2); d2 = fmaf(av.w, w2.w, d2);
    d3 = fmaf(av.x, w3.x, d3); d3 = fmaf(av.y, w3.y, d3); d3 = fmaf(av.z, w3.z, d3); d3 = fmaf(av.w, w3.w, d3);
    ct = fmaf(av.x, wc.x, ct); ct = fmaf(av.y, wc.y, ct); ct = fmaf(av.z, wc.z, ct); ct = fmaf(av.w, wc.w, ct);
  }
  float sl = scales[level];
  float* dd = deltas + ((size_t)n * 10000 + p) * 4;
  dd[0] = sl * (d0 + bb[0]); dd[1] = sl * (d1 + bb[1]);
  dd[2] = sl * (d2 + bb[2]); dd[3] = sl * (d3 + bb[3]);
  float sct = sigf(ct + bc[0]);
  float* sp = score + (size_t)n * HW * 80 + (size_t)p * 80;
#pragma unroll
  for (int i = 0; i < 20; ++i) {
    float4 v = ((float4*)sp)[i];
    v.x *= sct; v.y *= sct; v.z *= sct; v.w *= sct;
    v.x = (v.x > 0.05f) ? v.x : 0.f;
    v.y = (v.y > 0.05f) ? v.y : 0.f;
    v.z = (v.z > 0.05f) ? v.z : 0.f;
    v.w = (v.w > 0.05f) ? v.w : 0.f;
    ((float4*)sp)[i] = v;
  }
}

// ==================== exact top-1000 select: 3-pass bit histogram ====================
// thr[n][8]: 0:B1 1:B2 2:above 3:T 4:need_eq 5:cnt_gt 6:cnt_eq 7:spare
__global__ __launch_bounds__(256) void hist_k(const float* __restrict__ score, int M,
                                              const unsigned* __restrict__ thr,
                                              unsigned* __restrict__ hist, int phase)
{
  const int n = blockIdx.y;
  const float* s = score + (size_t)n * M;
  unsigned* h = hist + n * 2048;
  const unsigned* tr = thr + n * 8;
  __shared__ unsigned lh[2048];
  for (int i = threadIdx.x; i < 2048; i += 256) lh[i] = 0u;
  __syncthreads();
  unsigned B1 = 0, pref = 0;
  if (phase == 1) B1 = tr[0];
  if (phase == 2) pref = (tr[0] << 11) | tr[1];
  for (int idx = blockIdx.x * 256 + threadIdx.x; idx < M; idx += gridDim.x * 256) {
    float v = s[idx];
    if (v > 0.f) {
      unsigned b = __float_as_uint(v);
      if (phase == 0) atomicAdd(&lh[b >> 20], 1u);
      else if (phase == 1) { if ((b >> 20) == B1) atomicAdd(&lh[(b >> 9) & 0x7FFu], 1u); }
      else { if ((b >> 9) == pref) atomicAdd(&lh[b & 0x1FFu], 1u); }
    }
  }
  __syncthreads();
  for (int i = threadIdx.x; i < 2048; i += 256) { unsigned v = lh[i]; if (v) atomicAdd(&h[i], v); }
}

__global__ __launch_bounds__(256) void scan_k(unsigned* __restrict__ hist,
                                              unsigned* __restrict__ thr, int phase)
{
  const int n = blockIdx.x, t = threadIdx.x;
  unsigned* h  = hist + n * 2048;
  unsigned* tr = thr + n * 8;
  const int nb = (phase == 2) ? 512 : 2048;
  const int PB = nb / 256;
  unsigned target = 1000u;
  bool dead = false;
  if (phase >= 1) {
    target = 1000u - tr[2];
    if (tr[0] == 0xFFFFFFFFu) dead = true;
    if (phase == 2 && tr[1] == 0xFFFFFFFFu) dead = true;
  }
  __shared__ unsigned ps[256];
  __shared__ unsigned s_tot;
  const int hi = nb - t * PB;
  unsigned lsum = 0;
  for (int k = 0; k < PB; ++k) lsum += h[hi - 1 - k];
  ps[t] = lsum;
  __syncthreads();
  if (t == 0) {
    unsigned cum = 0;
    for (int i = 0; i < 256; ++i) { unsigned tmp = ps[i]; ps[i] = cum; cum += tmp; }
    s_tot = cum;
  }
  __syncthreads();
  unsigned exc = ps[t], tot = s_tot;
  if (!dead && tot >= target) {
    if (exc < target && exc + lsum >= target) {
      unsigned cum = exc; int bf = 0; unsigned above = 0;
      for (int k = 0; k < PB; ++k) {
        int bidx = hi - 1 - k;
        unsigned c = h[bidx];
        if (cum < target && cum + c >= target) { bf = bidx; above = cum; }
        cum += c;
      }
      if (phase == 0)      { tr[0] = (unsigned)bf; tr[2] = above; }
      else if (phase == 1) { tr[1] = (unsigned)bf; tr[2] = tr[2] + above; }
      else {
        unsigned T = (tr[0] << 20) | (tr[1] << 9) | (unsigned)bf;
        tr[3] = T; tr[4] = target - above;
      }
    }
  } else if (t == 0) {
    if (phase == 0)      { tr[0] = 0xFFFFFFFFu; tr[2] = 0u; }
    else if (phase == 1) { tr[1] = 0xFFFFFFFFu; }
    else                 { tr[3] = 0u; tr[4] = 0u; }
  }
  if (phase == 2 && t == 0) { tr[5] = 0u; tr[6] = 0u; }
}

// ==================== select + decode into candidate arrays ====================
__global__ __launch_bounds__(256) void select_k(const float* __restrict__ score,
                                                const float* __restrict__ deltas,
                                                unsigned* __restrict__ thr,
                                                float* __restrict__ cbox, float* __restrict__ csc,
                                                float* __restrict__ ccls, float* __restrict__ cgid,
                                                int M, int W, float stride_, int level)
{
  const int n = blockIdx.y;
  const float* s = score + (size_t)n * M;
  unsigned* tr = thr + n * 8;
  const unsigned T = tr[3], need = tr[4];
  for (int idx = blockIdx.x * 256 + threadIdx.x; idx < M; idx += gridDim.x * 256) {
    float v = s[idx];
    if (!(v > 0.f)) continue;
    unsigned b = __float_as_uint(v);
    int slot = -1;
    if (b > T) slot = (int)atomicAdd(&tr[5], 1u);
    else if (b == T) {
      unsigned e = atomicAdd(&tr[6], 1u);
      if (e < need) slot = (int)(1000u - need + e);
    }
    if (slot < 0) continue;
    int p = idx / 80, c = idx - p * 80;
    int y = p / W, x = p - y * W;
    const float* d = deltas + ((size_t)n * 10000 + p) * 4;
    float sz  = 8.f * stride_;
    float acx = ((float)x + 0.5f) * stride_;
    float acy = ((float)y + 0.5f) * stride_;
    float dx = d[0] / 10.f, dy = d[1] / 10.f;
    float dw = fminf(d[2] / 5.f, SCALE_CLAMP);
    float dh = fminf(d[3] / 5.f, SCALE_CLAMP);
    float pcx = dx * sz + acx;
    float pcy = dy * sz + acy;
    float pw = expf(dw) * sz;
    float ph = expf(dh) * sz;
    float x1 = pcx - 0.5f * pw, y1_ = pcy - 0.5f * ph;
    float x2 = pcx + 0.5f * pw, y2_ = pcy + 0.5f * ph;
    x1  = fminf(fmaxf(x1, 0.f),  IMG_SIZE);
    y1_ = fminf(fmaxf(y1_, 0.f), IMG_SIZE);
    x2  = fminf(fmaxf(x2, 0.f),  IMG_SIZE);
    y2_ = fminf(fmaxf(y2_, 0.f), IMG_SIZE);
    int cslot = n * 5000 + level * 1000 + slot;
    ((float4*)cbox)[cslot] = make_float4(x1, y1_, x2, y2_);
    csc[cslot]  = sqrtf(v);
    ccls[cslot] = (float)c;
    cgid[cslot] = (float)(((unsigned)level << 20) | (unsigned)idx);
  }
}

// ==================== class-aware greedy NMS, 100 iterations, one block per image ====================
__global__ __launch_bounds__(256) void nms_k(const float* __restrict__ cbox,
                                             const float* __restrict__ csc,
                                             const float* __restrict__ ccls,
                                             const float* __restrict__ cgid,
                                             float* __restrict__ outp)
{
  const int n = blockIdx.x, t = threadIdx.x;
  float sc[20], cl[20], gid[20], bx[20][4];
#pragma unroll
  for (int j = 0; j < 20; ++j) {
    int g = j * 256 + t;
    if (g < 5000) {
      sc[j] = csc[n * 5000 + g];
      float4 b = ((const float4*)cbox)[n * 5000 + g];
      bx[j][0] = b.x; bx[j][1] = b.y; bx[j][2] = b.z; bx[j][3] = b.w;
      cl[j]  = ccls[n * 5000 + g];
      gid[j] = cgid[n * 5000 + g];
    } else { sc[j] = -2.f; bx[j][0] = bx[j][1] = bx[j][2] = bx[j][3] = 0.f; cl[j] = 0.f; gid[j] = 1e9f; }
  }
  __shared__ float rv[4]; __shared__ int rg[4]; __shared__ float rgid[4];
  __shared__ float sbox[4]; __shared__ float scls; __shared__ float sval; __shared__ int sgi;

  for (int it = 0; it < 100; ++it) {
    float bv = -3.f; int bg = 0; float bgid = 2e9f;
#pragma unroll
    for (int j = 0; j < 20; ++j) {
      bool better = (sc[j] > bv) || (sc[j] == bv && gid[j] < bgid);
      if (better) { bv = sc[j]; bg = j * 256 + t; bgid = gid[j]; }
    }
    for (int off = 32; off; off >>= 1) {
      float ov = __shfl_xor(bv, off);
      int   og = __shfl_xor(bg, off);
      float oi = __shfl_xor(bgid, off);
      bool better = (ov > bv) || (ov == bv && oi < bgid);
      if (better) { bv = ov; bg = og; bgid = oi; }
    }
    int wid = t >> 6;
    if ((t & 63) == 0) { rv[wid] = bv; rg[wid] = bg; rgid[wid] = bgid; }
    __syncthreads();
    if (t == 0) {
      float fv = rv[0]; int fg = rg[0]; float fi = rgid[0];
      for (int w = 1; w < 4; ++w) {
        bool better = (rv[w] > fv) || (rv[w] == fv && rgid[w] < fi);
        if (better) { fv = rv[w]; fg = rg[w]; fi = rgid[w]; }
      }
      sval = fv; sgi = fg;
    }
    __syncthreads();
    float best_v = sval; int best_g = sgi;
    if (t == (best_g & 255)) {
      int j = best_g >> 8;
      sbox[0] = bx[j][0]; sbox[1] = bx[j][1]; sbox[2] = bx[j][2]; sbox[3] = bx[j][3];
      scls = cl[j];
    }
    __syncthreads();
    bool valid = best_v > 0.f;
    if (t == 0) {
      int base = n * 100 + it;
      outp[base * 4 + 0] = valid ? sbox[0] : 0.f;
      outp[base * 4 + 1] = valid ? sbox[1] : 0.f;
      outp[base * 4 + 2] = valid ? sbox[2] : 0.f;
      outp[base * 4 + 3] = valid ? sbox[3] : 0.f;
      outp[1600 + base] = valid ? best_v : 0.f;
      outp[2000 + base] = valid ? scls : -1.f;
    }
    float off_ = scls * (2.f * IMG_SIZE);
    float e0 = sbox[0] + off_, e1 = sbox[1] + off_, e2 = sbox[2] + off_, e3 = sbox[3] + off_;
    float a1 = (e2 - e0) * (e3 - e1);
#pragma unroll
    for (int j = 0; j < 20; ++j) {
      float o_ = cl[j] * (2.f * IMG_SIZE);
      float f0 = bx[j][0] + o_, f1 = bx[j][1] + o_, f2 = bx[j][2] + o_, f3 = bx[j][3] + o_;
      float xx1 = fmaxf(e0, f0), yy1 = fmaxf(e1, f1);
      float xx2 = fminf(e2, f2), yy2 = fminf(e3, f3);
      float inter = fmaxf(xx2 - xx1, 0.f) * fmaxf(yy2 - yy1, 0.f);
      float a2 = (f2 - f0) * (f3 - f1);
      float iou = inter / (a1 + a2 - inter + 1e-9f);
      if (iou > 0.6f) sc[j] = -1.f;
      if ((j * 256 + t) == best_g) sc[j] = -1.f;
    }
    __syncthreads();
  }
}

// ==================== host orchestration ====================
template<int H, int W, int PC, int PJ>
static void run_level(int l, const float* feat, const float* wt,
                      const float* cls_tb, const float* bbox_tb,
                      const float* wcls, const float* bcls,
                      const float* wbox, const float* bbox_b,
                      const float* wctr, const float* bctr,
                      const float* scales,
                      float* bufA, float* bufB, float* score, float* deltas,
                      float* cbox, float* csc, float* ccls, float* cgid,
                      unsigned* hist, unsigned* thr, hipStream_t stream)
{
  constexpr int PW = W + 2;
  constexpr int PHW = (H + 2) * (W + 2);
  constexpr int HW = H * W;
  const int M = HW * 80;
  const size_t bufBytes = 4ull * PHW * 256 * 4;
  hipMemsetAsync(bufA, 0, bufBytes, stream);
  hipMemsetAsync(bufB, 0, bufBytes, stream);
  const int chunks = (HW + PC - 1) / PC;
  dim3 cg(chunks, 2, 4);
  // cls tower
  conv3x3_k<H,W,PC,PJ,true ><<<cg,256,0,stream>>>(feat, wt + 0ull*589824, cls_tb + 0*256, bufA);
  conv3x3_k<H,W,PC,PJ,false><<<cg,256,0,stream>>>(bufA, wt + 1ull*589824, cls_tb + 1*256, bufB);
  conv3x3_k<H,W,PC,PJ,false><<<cg,256,0,stream>>>(bufB, wt + 2ull*589824, cls_tb + 2*256, bufA);
  conv3x3_k<H,W,PC,PJ,false><<<cg,256,0,stream>>>(bufA, wt + 3ull*589824, cls_tb + 3*256, bufB);
  cls_head_k<<<dim3((HW + 63) / 64, 4), 256, 0, stream>>>(bufB, wcls, bcls, score, HW, W, PW, PHW);
  // bbox tower
  conv3x3_k<H,W,PC,PJ,true ><<<cg,256,0,stream>>>(feat, wt + 4ull*589824, bbox_tb + 0*256, bufA);
  conv3x3_k<H,W,PC,PJ,false><<<cg,256,0,stream>>>(bufA, wt + 5ull*589824, bbox_tb + 1*256, bufB);
  conv3x3_k<H,W,PC,PJ,false><<<cg,256,0,stream>>>(bufB, wt + 6ull*589824, bbox_tb + 2*256, bufA);
  conv3x3_k<H,W,PC,PJ,false><<<cg,256,0,stream>>>(bufA, wt + 7ull*589824, bbox_tb + 3*256, bufB);
  box_head_k<<<dim3((HW + 255) / 256, 4), 256, 0, stream>>>(bufB, wbox, bbox_b, wctr, bctr,
                                                            scales, l, score, deltas, HW, W, PW, PHW);
  // exact top-1000 per (level, image)
  int hb = (M + 4095) / 4096; if (hb > 512) hb = 512; if (hb < 1) hb = 1;
  for (int phase = 0; phase < 3; ++phase) {
    hipMemsetAsync(hist, 0, 4ull * 2048 * 4, stream);
    hist_k<<<dim3(hb, 4), 256, 0, stream>>>(score, M, thr, hist, phase);
    scan_k<<<4, 256, 0, stream>>>(hist, thr, phase);
  }
  float stride_ = (float)(8 << l);
  select_k<<<dim3(hb, 4), 256, 0, stream>>>(score, deltas, thr, cbox, csc, ccls, cgid,
                                            M, W, stride_, l);
}

extern "C" void kernel_launch(void* const* d_in, const int* in_sizes, int n_in,
                              void* d_out, int out_size, void* d_ws, size_t ws_size,
                              hipStream_t stream)
{
  (void)in_sizes; (void)n_in; (void)out_size; (void)ws_size;
  const float* feats[5] = { (const float*)d_in[0], (const float*)d_in[1], (const float*)d_in[2],
                            (const float*)d_in[3], (const float*)d_in[4] };
  const float* cls_tw  = (const float*)d_in[5];
  const float* cls_tb  = (const float*)d_in[6];
  const float* bbox_tw = (const float*)d_in[7];
  const float* bbox_tb = (const float*)d_in[8];
  const float* wcls    = (const float*)d_in[9];
  const float* bcls    = (const float*)d_in[10];
  const float* wbox    = (const float*)d_in[11];
  const float* bbox_b  = (const float*)d_in[12];
  const float* wctr    = (const float*)d_in[13];
  const float* bctr    = (const float*)d_in[14];
  const float* scales  = (const float*)d_in[15];
  float* out = (float*)d_out;

  char* ws = (char*)d_ws;
  size_t off = 0;
  auto alloc = [&](size_t bytes) -> void* {
    off = (off + 255) & ~(size_t)255;
    void* p = ws + off; off += bytes; return p;
  };
  float* bufA   = (float*)alloc(4ull * 102 * 102 * 256 * 4);
  float* bufB   = (float*)alloc(4ull * 102 * 102 * 256 * 4);
  float* wt     = (float*)alloc(8ull * 589824 * 4);
  float* score  = (float*)alloc(4ull * 800000 * 4);
  float* deltas = (float*)alloc(4ull * 10000 * 4 * 4);
  float* cbox   = (float*)alloc(4ull * 5000 * 4 * 4);
  float* csc    = (float*)alloc(4ull * 5000 * 4);
  float* ccls   = (float*)alloc(4ull * 5000 * 4);
  float* cgid   = (float*)alloc(4ull * 5000 * 4);
  unsigned* hist = (unsigned*)alloc(4ull * 2048 * 4);
  unsigned* thr  = (unsigned*)alloc(4ull * 8 * 4);

  hipMemsetAsync(cbox, 0, 4ull * 5000 * 4 * 4, stream);
  hipMemsetAsync(csc,  0, 4ull * 5000 * 4, stream);
  hipMemsetAsync(ccls, 0, 4ull * 5000 * 4, stream);
  hipMemsetAsync(cgid, 0, 4ull * 5000 * 4, stream);
  hipMemsetAsync(thr,  0, 4ull * 8 * 4, stream);

  wtrans_k<<<2048, 256, 0, stream>>>(cls_tw, bbox_tw, wt);

  run_level<100,100,128,8>(0, feats[0], wt, cls_tb, bbox_tb, wcls, bcls, wbox, bbox_b,
                           wctr, bctr, scales, bufA, bufB, score, deltas,
                           cbox, csc, ccls, cgid, hist, thr, stream);
  run_level< 50, 50, 64,4>(1, feats[1], wt, cls_tb, bbox_tb, wcls, bcls, wbox, bbox_b,
                           wctr, bctr, scales, bufA, bufB, score, deltas,
                           cbox, csc, ccls, cgid, hist, thr, stream);
  run_level< 25, 25, 32,2>(2, feats[2], wt, cls_tb, bbox_tb, wcls, bcls, wbox, bbox_b,
                           wctr, bctr, scales, bufA, bufB, score, deltas,
                           cbox, csc, ccls, cgid, hist, thr, stream);
  run_level< 13, 13, 16,1>(3, feats[3], wt, cls_tb, bbox_tb, wcls, bcls, wbox, bbox_b,
                           wctr, bctr, scales, bufA, bufB, score, deltas,
                           cbox, csc, ccls, cgid, hist, thr, stream);
  run_level<  7,  7, 16,1>(4, feats[4], wt, cls_tb, bbox_tb, wcls, bcls, wbox, bbox_b,
                           wctr, bctr, scales, bufA, bufB, score, deltas,
                           cbox, csc, ccls, cgid, hist, thr, stream);

  nms_k<<<4, 256, 0, stream>>>(cbox, csc, ccls, cgid, out);
}

// Round 3
// 6010.762 us; speedup vs baseline: 3.3339x; 3.3339x over previous
//
#include <hip/hip_runtime.h>
#include <math.h>

typedef short s8v __attribute__((ext_vector_type(8)));
typedef float f4v __attribute__((ext_vector_type(4)));

__device__ __forceinline__ float sigf(float x) { return 1.f / (1.f + expf(-x)); }

#define SCALE_CLAMP 4.135166556742356f
#define IMG_SIZE 800.f

// 3-way bf16 split: x ~= h + m + l, |x-(h+m+l)| <= ~2^-27 |x|
__device__ __forceinline__ void split3(float x, short& h, short& m, short& l) {
  unsigned u = __float_as_uint(x);
  unsigned hb = (u + 0x7FFFu + ((u >> 16) & 1u)) >> 16;
  float hf = __uint_as_float(hb << 16);
  float d1 = x - hf;
  unsigned u1 = __float_as_uint(d1);
  unsigned mb = (u1 + 0x7FFFu + ((u1 >> 16) & 1u)) >> 16;
  float mf = __uint_as_float(mb << 16);
  float d2 = d1 - mf;
  unsigned u2 = __float_as_uint(d2);
  unsigned lb = (u2 + 0x7FFFu + ((u2 >> 16) & 1u)) >> 16;
  h = (short)hb; m = (short)mb; l = (short)lb;
}

struct Geo {
  int tp[6];                 // conv tile prefix per level
  int TXa[5];
  int Ha[5], Wa[5], PWa[5], PHWa[5];
  int phwOff[5];             // PHW prefix
  int hwOff[5];              // HW prefix
  int pb[6];                 // ceil(HW/64) prefix  (prep + cls head)
  int bb[6];                 // ceil(HW/256) prefix (box head)
};

// ==================== weight split+transpose ====================
// out layout (bf16 shorts): [layer8][plane3][ (tap*8+cc)*4+q ][ko 256][e 8]
// plane stride 589824, layer stride 1769472. ci = cc*32 + q*8 + e.
__global__ __launch_bounds__(256) void wtrans_k(const float* __restrict__ cls_tw,
                                                const float* __restrict__ bbox_tw,
                                                short* __restrict__ wt)
{
  const int total = 589824; // 8 layers * 9 tap * 8 cc * 4 q * 256 ko
  for (int u = blockIdx.x * 256 + threadIdx.x; u < total; u += gridDim.x * 256) {
    int layer = u / 73728;
    int r = u - layer * 73728;
    int tap = r / 8192;  r -= tap * 8192;
    int cc  = r / 1024;  r -= cc * 1024;
    int qq  = r / 256;   int ko = r - qq * 256;
    int cibase = cc * 32 + qq * 8;
    const float* src = (layer < 4) ? (cls_tw + (size_t)layer * 589824)
                                   : (bbox_tw + (size_t)(layer - 4) * 589824);
    s8v hv, mv, lv;
#pragma unroll
    for (int e = 0; e < 8; ++e) {
      float x = src[(size_t)ko * 2304 + (size_t)(cibase + e) * 9 + tap];
      short h, m, l; split3(x, h, m, l);
      hv[e] = h; mv[e] = m; lv[e] = l;
    }
    size_t dbase = (size_t)layer * 1769472 + (((size_t)tap * 8 + cc) * 4 + qq) * 2048 + (size_t)ko * 8;
    *(s8v*)(wt + dbase) = hv;
    *(s8v*)(wt + dbase + 589824) = mv;
    *(s8v*)(wt + dbase + 2 * 589824) = lv;
  }
}

// ==================== NCHW -> padded NHWC fp32 (all levels) ====================
__global__ __launch_bounds__(256) void prep_all_k(const float* __restrict__ p3, const float* __restrict__ p4,
                                                  const float* __restrict__ p5, const float* __restrict__ p6,
                                                  const float* __restrict__ p7,
                                                  float* __restrict__ out, Geo g)
{
  __shared__ float tl[64][260];
  int bx = blockIdx.x, t = threadIdx.x, n = blockIdx.y;
  int l = 0; while (l < 4 && bx >= g.pb[l + 1]) ++l;
  const float* in = (l == 0) ? p3 : (l == 1) ? p4 : (l == 2) ? p5 : (l == 3) ? p6 : p7;
  int H = g.Ha[l], W = g.Wa[l], PW = g.PWa[l], PHW = g.PHWa[l], HW = H * W;
  int P0 = (bx - g.pb[l]) * 64;
  const float* inN = in + (size_t)n * HW * 256;
  int sub = t >> 6, pl = t & 63;
  int pos = P0 + pl;
  for (int i = 0; i < 64; ++i) {
    int ci = i * 4 + sub;
    tl[pl][ci] = (pos < HW) ? inN[(size_t)ci * HW + pos] : 0.f;
  }
  __syncthreads();
  int pl2 = t >> 2, cq = (t & 3) * 64;
  int pos2 = P0 + pl2;
  if (pos2 < HW) {
    int y = pos2 / W, x = pos2 - y * W;
    float* o = out + (((size_t)g.phwOff[l] * 4 + (size_t)n * PHW) + (size_t)(y + 1) * PW + (x + 1)) * 256 + cq;
#pragma unroll
    for (int j = 0; j < 16; ++j) ((float4*)o)[j] = *(const float4*)&tl[pl2][cq + j * 4];
  }
}

// ==================== MFMA conv 3x3 + bias + relu (all levels, one layer) ====================
// in/out: padded NHWC fp32. Weights: pre-split bf16x3, layout per wtrans_k.
// Block: 8x16 position tile x 128 ko. 4 waves, each 8x8 pos x 64 ko.
// 6 MFMA products per fragment pair recover ~fp32 precision (err ~2^-26).
__global__ __launch_bounds__(256, 2) void conv_all_k(const float* __restrict__ in,
                                                     const short* __restrict__ wtL,
                                                     const float* __restrict__ bias,
                                                     float* __restrict__ out, Geo g)
{
  __shared__ short act_s[3 * 720 * 8];  // [plane][q*180+pos][8ci], pos in 10x18 halo
  __shared__ short w_s[3 * 512 * 8];    // [plane][q*128+ko][8ci]

  const int t = threadIdx.x;
  const int lane = t & 63, wave = t >> 6;
  const int wcol = wave & 1, wko = wave >> 1;
  const int n = blockIdx.z;
  const int ko0 = blockIdx.y * 128;
  int bx = blockIdx.x;
  int l = 0; while (l < 4 && bx >= g.tp[l + 1]) ++l;
  const int H = g.Ha[l], W = g.Wa[l], PW = g.PWa[l], PHW = g.PHWa[l];
  const int lt = bx - g.tp[l];
  const int TX = g.TXa[l];
  const int ty = lt / TX, tx = lt - ty * TX;
  const int R0 = ty * 8, C0 = tx * 16;
  const float* inN = in + ((size_t)g.phwOff[l] * 4 + (size_t)n * PHW) * 256;
  float* outN = out + ((size_t)g.phwOff[l] * 4 + (size_t)n * PHW) * 256;

  const int r = lane & 15, q = lane >> 4;
  const int cb = wcol * 8;

  f4v acc[4][4];
#pragma unroll
  for (int mi = 0; mi < 4; ++mi)
#pragma unroll
    for (int ni = 0; ni < 4; ++ni) { f4v z = {0.f, 0.f, 0.f, 0.f}; acc[mi][ni] = z; }

  auto stageAct = [&](int cc) {
    for (int j = t; j < 720; j += 256) {
      int qq = j / 180;
      int pos = j - qq * 180;
      int row = pos / 18;
      int col = pos - row * 18;
      int prow = R0 + row; if (prow > H + 1) prow = H + 1;
      int pcol = C0 + col; if (pcol > W + 1) pcol = W + 1;
      const float* gp = inN + ((size_t)prow * PW + pcol) * 256 + cc * 32 + qq * 8;
      float4 v0 = ((const float4*)gp)[0];
      float4 v1 = ((const float4*)gp)[1];
      float xs[8] = {v0.x, v0.y, v0.z, v0.w, v1.x, v1.y, v1.z, v1.w};
      s8v hv, mv, lv;
#pragma unroll
      for (int e = 0; e < 8; ++e) {
        short h, m, lo; split3(xs[e], h, m, lo);
        hv[e] = h; mv[e] = m; lv[e] = lo;
      }
      *(s8v*)&act_s[j * 8] = hv;
      *(s8v*)&act_s[(720 + j) * 8] = mv;
      *(s8v*)&act_s[(1440 + j) * 8] = lv;
    }
  };

  int4 wreg[6];
  auto loadW = [&](int cc2, int tap2) {
#pragma unroll
    for (int i = 0; i < 6; ++i) {
      int s = i * 256 + t;
      int p = s >> 9, rr = s & 511, qq = rr >> 7, ko = rr & 127;
      wreg[i] = *(const int4*)(wtL + (size_t)p * 589824 +
                               (((size_t)tap2 * 8 + cc2) * 4 + qq) * 2048 + (size_t)(ko0 + ko) * 8);
    }
  };
  auto writeW = [&]() {
#pragma unroll
    for (int i = 0; i < 6; ++i) *(int4*)&w_s[(i * 256 + t) * 8] = wreg[i];
  };

  // prologue
  stageAct(0);
  loadW(0, 0);
  writeW();
  __syncthreads();

  int cc = 0, tap = 0;
  for (int ks = 0; ks < 72; ++ks) {
    int ntap = tap + 1, ncc = cc;
    if (ntap == 9) { ntap = 0; ++ncc; }
    const bool hn = (ks < 71);
    if (hn) loadW(ncc, ntap);   // global prefetch, consumed after barrier

    // fragment loads + 96 MFMAs
    {
      const int dy = tap / 3, dx = tap - dy * 3;
      s8v afr[3][4], bfr[3][4];
#pragma unroll
      for (int mi = 0; mi < 4; ++mi) {
        int sl = q * 180 + (2 * mi + (r >> 3) + dy) * 18 + (cb + (r & 7) + dx);
        afr[0][mi] = *(const s8v*)&act_s[sl * 8];
        afr[1][mi] = *(const s8v*)&act_s[(720 + sl) * 8];
        afr[2][mi] = *(const s8v*)&act_s[(1440 + sl) * 8];
      }
#pragma unroll
      for (int ni = 0; ni < 4; ++ni) {
        int sl = q * 128 + wko * 64 + ni * 16 + r;
        bfr[0][ni] = *(const s8v*)&w_s[sl * 8];
        bfr[1][ni] = *(const s8v*)&w_s[(512 + sl) * 8];
        bfr[2][ni] = *(const s8v*)&w_s[(1024 + sl) * 8];
      }
      const int PA[6] = {0, 0, 1, 1, 0, 2};
      const int PB[6] = {0, 1, 0, 1, 2, 0};
#pragma unroll
      for (int pp = 0; pp < 6; ++pp) {
#pragma unroll
        for (int mi = 0; mi < 4; ++mi)
#pragma unroll
          for (int ni = 0; ni < 4; ++ni)
            acc[mi][ni] = __builtin_amdgcn_mfma_f32_16x16x32_bf16(
                afr[PA[pp]][mi], bfr[PB[pp]][ni], acc[mi][ni], 0, 0, 0);
      }
    }
    __syncthreads();            // all waves done reading act_s/w_s
    if (hn) {
      if (ntap == 0) stageAct(ncc);
      writeW();
      __syncthreads();          // staging visible
    }
    tap = ntap; cc = ncc;
  }

  // epilogue: bias + relu, masked store
#pragma unroll
  for (int mi = 0; mi < 4; ++mi) {
#pragma unroll
    for (int ni = 0; ni < 4; ++ni) {
      int ko = ko0 + wko * 64 + ni * 16 + r;
      float bv = bias[ko];
#pragma unroll
      for (int reg = 0; reg < 4; ++reg) {
        int rm = q * 4 + reg;
        int orow = R0 + 2 * mi + (rm >> 3);
        int ocol = C0 + cb + (rm & 7);
        if (orow < H && ocol < W) {
          float vv = acc[mi][ni][reg] + bv;
          outN[((size_t)(orow + 1) * PW + (ocol + 1)) * 256 + ko] = fmaxf(vv, 0.f);
        }
      }
    }
  }
}

// ==================== cls head (all levels): 1x1x80 + sigmoid ====================
__global__ __launch_bounds__(256) void cls_head_k(const float* __restrict__ act,
                                                  const float* __restrict__ wcls,
                                                  const float* __restrict__ bcls,
                                                  float* __restrict__ score, Geo g)
{
  __shared__ int   p2s[64];
  __shared__ float as_[64][69];
  __shared__ float ws_[64][84];
  const int t = threadIdx.x;
  const int n = blockIdx.y;
  int bx = blockIdx.x;
  int l = 0; while (l < 4 && bx >= g.pb[l + 1]) ++l;
  const int H = g.Ha[l], W = g.Wa[l], PW = g.PWa[l], PHW = g.PHWa[l], HW = H * W;
  const int P0 = (bx - g.pb[l]) * 64;
  if (t < 64) {
    int p = P0 + t; if (p >= HW) p = HW - 1;
    int y = p / W, x = p - y * W;
    p2s[t] = (y + 1) * PW + x + 1;
  }
  __syncthreads();
  float accv[4][5];
#pragma unroll
  for (int i = 0; i < 4; ++i)
#pragma unroll
    for (int j = 0; j < 5; ++j) accv[i][j] = 0.f;

  const float* actN = act + ((size_t)g.phwOff[l] * 4 + (size_t)n * PHW) * 256;
  const int pg = t >> 4, cg = t & 15;

  for (int c0 = 0; c0 < 256; c0 += 64) {
    for (int i = t; i < 1024; i += 256) {
      int pos = i >> 4, c4 = i & 15;
      float4 v = *(const float4*)(actN + (size_t)p2s[pos] * 256 + c0 + c4 * 4);
      float* dst = &as_[pos][c4 * 4];
      dst[0] = v.x; dst[1] = v.y; dst[2] = v.z; dst[3] = v.w;
    }
    for (int i = t; i < 1280; i += 256) {
      int c = i >> 4, c4 = i & 15;
      float4 v = *(const float4*)(wcls + (size_t)c * 256 + c0 + c4 * 4);
      ws_[c4 * 4 + 0][c] = v.x; ws_[c4 * 4 + 1][c] = v.y;
      ws_[c4 * 4 + 2][c] = v.z; ws_[c4 * 4 + 3][c] = v.w;
    }
    __syncthreads();
#pragma unroll 8
    for (int ci = 0; ci < 64; ++ci) {
#pragma unroll
      for (int i = 0; i < 4; ++i) {
        float a = as_[pg * 4 + i][ci];
#pragma unroll
        for (int j = 0; j < 5; ++j)
          accv[i][j] = fmaf(a, ws_[ci][cg * 5 + j], accv[i][j]);
      }
    }
    __syncthreads();
  }
  float* sB = score + ((size_t)g.hwOff[l] * 4 + (size_t)n * HW) * 80;
#pragma unroll
  for (int i = 0; i < 4; ++i) {
    int p = P0 + pg * 4 + i;
    if (p >= HW) continue;
#pragma unroll
    for (int j = 0; j < 5; ++j) {
      int c = cg * 5 + j;
      sB[(size_t)p * 80 + c] = sigf(accv[i][j] + bcls[c]);
    }
  }
}

// ==================== box head (all levels) ====================
__global__ __launch_bounds__(256) void box_head_k(const float* __restrict__ act,
                                                  const float* __restrict__ wbox,
                                                  const float* __restrict__ bb,
                                                  const float* __restrict__ wctr,
                                                  const float* __restrict__ bc,
                                                  const float* __restrict__ scales,
                                                  float* __restrict__ score,
                                                  float* __restrict__ deltas, Geo g)
{
  int n = blockIdx.y;
  int bx = blockIdx.x;
  int l = 0; while (l < 4 && bx >= g.bb[l + 1]) ++l;
  const int H = g.Ha[l], W = g.Wa[l], PW = g.PWa[l], PHW = g.PHWa[l], HW = H * W;
  int p = (bx - g.bb[l]) * 256 + threadIdx.x;
  if (p >= HW) return;
  int y = p / W, x = p - y * W;
  const float* a = act + (((size_t)g.phwOff[l] * 4 + (size_t)n * PHW) + (size_t)(y + 1) * PW + x + 1) * 256;
  float d0 = 0, d1 = 0, d2 = 0, d3 = 0, ct = 0;
  for (int i = 0; i < 64; ++i) {
    float4 av = ((const float4*)a)[i];
    float4 w0 = ((const float4*)wbox)[0 * 64 + i];
    float4 w1 = ((const float4*)wbox)[1 * 64 + i];
    float4 w2 = ((const float4*)wbox)[2 * 64 + i];
    float4 w3 = ((const float4*)wbox)[3 * 64 + i];
    float4 wc = ((const float4*)wctr)[i];
    d0 = fmaf(av.x, w0.x, d0); d0 = fmaf(av.y, w0.y, d0); d0 = fmaf(av.z, w0.z, d0); d0 = fmaf(av.w, w0.w, d0);
    d1 = fmaf(av.x, w1.x, d1); d1 = fmaf(av.y, w1.y, d1); d1 = fmaf(av.z, w1.z, d1); d1 = fmaf(av.w, w1.w, d1);
    d2 = fmaf(av.x, w2.x, d2); d2 = fmaf(av.y, w2.y, d2); d2 = fmaf(av.z, w2.z, d2); d2 = fmaf(av.w, w2.w, d2);
    d3 = fmaf(av.x, w3.x, d3); d3 = fmaf(av.y, w3.y, d3); d3 = fmaf(av.z, w3.z, d3); d3 = fmaf(av.w, w3.w, d3);
    ct = fmaf(av.x, wc.x, ct); ct = fmaf(av.y, wc.y, ct); ct = fmaf(av.z, wc.z, ct); ct = fmaf(av.w, wc.w, ct);
  }
  float sl = scales[l];
  float* dd = deltas + ((size_t)g.hwOff[l] * 4 + (size_t)n * HW + p) * 4;
  dd[0] = sl * (d0 + bb[0]); dd[1] = sl * (d1 + bb[1]);
  dd[2] = sl * (d2 + bb[2]); dd[3] = sl * (d3 + bb[3]);
  float sct = sigf(ct + bc[0]);
  float* sp = score + ((size_t)g.hwOff[l] * 4 + (size_t)n * HW + p) * 80;
#pragma unroll
  for (int i = 0; i < 20; ++i) {
    float4 v = ((float4*)sp)[i];
    v.x *= sct; v.y *= sct; v.z *= sct; v.w *= sct;
    v.x = (v.x > 0.05f) ? v.x : 0.f;
    v.y = (v.y > 0.05f) ? v.y : 0.f;
    v.z = (v.z > 0.05f) ? v.z : 0.f;
    v.w = (v.w > 0.05f) ? v.w : 0.f;
    ((float4*)sp)[i] = v;
  }
}

// ==================== exact top-1000: 3-pass bit histogram over 20 (level,image) groups ====================
__global__ __launch_bounds__(256) void hist_k(const float* __restrict__ score,
                                              const unsigned* __restrict__ thr,
                                              unsigned* __restrict__ hist, int phase, Geo g)
{
  const int grp = blockIdx.y;
  const int l = grp >> 2, n = grp & 3;
  const int HW = g.Ha[l] * g.Wa[l];
  const int M = HW * 80;
  const float* s = score + ((size_t)g.hwOff[l] * 4 + (size_t)n * HW) * 80;
  unsigned* h = hist + grp * 2048;
  const unsigned* tr = thr + grp * 8;
  __shared__ unsigned lh[2048];
  for (int i = threadIdx.x; i < 2048; i += 256) lh[i] = 0u;
  __syncthreads();
  unsigned B1 = 0, pref = 0;
  if (phase == 1) B1 = tr[0];
  if (phase == 2) pref = (tr[0] << 11) | tr[1];
  for (int idx = blockIdx.x * 256 + threadIdx.x; idx < M; idx += gridDim.x * 256) {
    float v = s[idx];
    if (v > 0.f) {
      unsigned b = __float_as_uint(v);
      if (phase == 0) atomicAdd(&lh[b >> 20], 1u);
      else if (phase == 1) { if ((b >> 20) == B1) atomicAdd(&lh[(b >> 9) & 0x7FFu], 1u); }
      else { if ((b >> 9) == pref) atomicAdd(&lh[b & 0x1FFu], 1u); }
    }
  }
  __syncthreads();
  for (int i = threadIdx.x; i < 2048; i += 256) { unsigned v = lh[i]; if (v) atomicAdd(&h[i], v); }
}

__global__ __launch_bounds__(256) void scan_k(unsigned* __restrict__ hist,
                                              unsigned* __restrict__ thr, int phase)
{
  const int grp = blockIdx.x, t = threadIdx.x;
  unsigned* h  = hist + grp * 2048;
  unsigned* tr = thr + grp * 8;
  const int nb = (phase == 2) ? 512 : 2048;
  const int PB = nb / 256;
  unsigned target = 1000u;
  bool dead = false;
  if (phase >= 1) {
    target = 1000u - tr[2];
    if (tr[0] == 0xFFFFFFFFu) dead = true;
    if (phase == 2 && tr[1] == 0xFFFFFFFFu) dead = true;
  }
  __shared__ unsigned ps[256];
  __shared__ unsigned s_tot;
  const int hi = nb - t * PB;
  unsigned lsum = 0;
  for (int k = 0; k < PB; ++k) lsum += h[hi - 1 - k];
  ps[t] = lsum;
  __syncthreads();
  if (t == 0) {
    unsigned cum = 0;
    for (int i = 0; i < 256; ++i) { unsigned tmp = ps[i]; ps[i] = cum; cum += tmp; }
    s_tot = cum;
  }
  __syncthreads();
  unsigned exc = ps[t], tot = s_tot;
  if (!dead && tot >= target) {
    if (exc < target && exc + lsum >= target) {
      unsigned cum = exc; int bf = 0; unsigned above = 0;
      for (int k = 0; k < PB; ++k) {
        int bidx = hi - 1 - k;
        unsigned c = h[bidx];
        if (cum < target && cum + c >= target) { bf = bidx; above = cum; }
        cum += c;
      }
      if (phase == 0)      { tr[0] = (unsigned)bf; tr[2] = above; }
      else if (phase == 1) { tr[1] = (unsigned)bf; tr[2] = tr[2] + above; }
      else {
        unsigned T = (tr[0] << 20) | (tr[1] << 9) | (unsigned)bf;
        tr[3] = T; tr[4] = target - above;
      }
    }
  } else if (t == 0) {
    if (phase == 0)      { tr[0] = 0xFFFFFFFFu; tr[2] = 0u; }
    else if (phase == 1) { tr[1] = 0xFFFFFFFFu; }
    else                 { tr[3] = 0u; tr[4] = 0u; }
  }
  if (phase == 2 && t == 0) { tr[5] = 0u; tr[6] = 0u; }
}

// ==================== select + decode ====================
__global__ __launch_bounds__(256) void select_k(const float* __restrict__ score,
                                                const float* __restrict__ deltas,
                                                unsigned* __restrict__ thr,
                                                float* __restrict__ cbox, float* __restrict__ csc,
                                                float* __restrict__ ccls, float* __restrict__ cgid,
                                                Geo g)
{
  const int grp = blockIdx.y;
  const int l = grp >> 2, n = grp & 3;
  const int W = g.Wa[l];
  const int HW = g.Ha[l] * W;
  const int M = HW * 80;
  const float stride_ = (float)(8 << l);
  const float* s = score + ((size_t)g.hwOff[l] * 4 + (size_t)n * HW) * 80;
  const float* dBase = deltas + ((size_t)g.hwOff[l] * 4 + (size_t)n * HW) * 4;
  unsigned* tr = thr + grp * 8;
  const unsigned T = tr[3], need = tr[4];
  for (int idx = blockIdx.x * 256 + threadIdx.x; idx < M; idx += gridDim.x * 256) {
    float v = s[idx];
    if (!(v > 0.f)) continue;
    unsigned b = __float_as_uint(v);
    int slot = -1;
    if (b > T) slot = (int)atomicAdd(&tr[5], 1u);
    else if (b == T) {
      unsigned e = atomicAdd(&tr[6], 1u);
      if (e < need) slot = (int)(1000u - need + e);
    }
    if (slot < 0) continue;
    int p = idx / 80, c = idx - p * 80;
    int y = p / W, x = p - y * W;
    const float* d = dBase + (size_t)p * 4;
    float sz  = 8.f * stride_;
    float acx = ((float)x + 0.5f) * stride_;
    float acy = ((float)y + 0.5f) * stride_;
    float dx = d[0] / 10.f, dy = d[1] / 10.f;
    float dw = fminf(d[2] / 5.f, SCALE_CLAMP);
    float dh = fminf(d[3] / 5.f, SCALE_CLAMP);
    float pcx = dx * sz + acx;
    float pcy = dy * sz + acy;
    float pw = expf(dw) * sz;
    float ph = expf(dh) * sz;
    float x1 = pcx - 0.5f * pw, y1_ = pcy - 0.5f * ph;
    float x2 = pcx + 0.5f * pw, y2_ = pcy + 0.5f * ph;
    x1  = fminf(fmaxf(x1, 0.f),  IMG_SIZE);
    y1_ = fminf(fmaxf(y1_, 0.f), IMG_SIZE);
    x2  = fminf(fmaxf(x2, 0.f),  IMG_SIZE);
    y2_ = fminf(fmaxf(y2_, 0.f), IMG_SIZE);
    int cslot = n * 5000 + l * 1000 + slot;
    ((float4*)cbox)[cslot] = make_float4(x1, y1_, x2, y2_);
    csc[cslot]  = sqrtf(v);
    ccls[cslot] = (float)c;
    cgid[cslot] = (float)(((unsigned)l << 20) | (unsigned)idx);
  }
}

// ==================== class-aware greedy NMS ====================
__global__ __launch_bounds__(256) void nms_k(const float* __restrict__ cbox,
                                             const float* __restrict__ csc,
                                             const float* __restrict__ ccls,
                                             const float* __restrict__ cgid,
                                             float* __restrict__ outp)
{
  const int n = blockIdx.x, t = threadIdx.x;
  float sc[20], cl[20], gid[20], bx[20][4];
#pragma unroll
  for (int j = 0; j < 20; ++j) {
    int gidx = j * 256 + t;
    if (gidx < 5000) {
      sc[j] = csc[n * 5000 + gidx];
      float4 b = ((const float4*)cbox)[n * 5000 + gidx];
      bx[j][0] = b.x; bx[j][1] = b.y; bx[j][2] = b.z; bx[j][3] = b.w;
      cl[j]  = ccls[n * 5000 + gidx];
      gid[j] = cgid[n * 5000 + gidx];
    } else { sc[j] = -2.f; bx[j][0] = bx[j][1] = bx[j][2] = bx[j][3] = 0.f; cl[j] = 0.f; gid[j] = 1e9f; }
  }
  __shared__ float rv[4]; __shared__ int rg[4]; __shared__ float rgid[4];
  __shared__ float sbox[4]; __shared__ float scls; __shared__ float sval; __shared__ int sgi;

  for (int it = 0; it < 100; ++it) {
    float bv = -3.f; int bg = 0; float bgid = 2e9f;
#pragma unroll
    for (int j = 0; j < 20; ++j) {
      bool better = (sc[j] > bv) || (sc[j] == bv && gid[j] < bgid);
      if (better) { bv = sc[j]; bg = j * 256 + t; bgid = gid[j]; }
    }
    for (int off = 32; off; off >>= 1) {
      float ov = __shfl_xor(bv, off);
      int   og = __shfl_xor(bg, off);
      float oi = __shfl_xor(bgid, off);
      bool better = (ov > bv) || (ov == bv && oi < bgid);
      if (better) { bv = ov; bg = og; bgid = oi; }
    }
    int wid = t >> 6;
    if ((t & 63) == 0) { rv[wid] = bv; rg[wid] = bg; rgid[wid] = bgid; }
    __syncthreads();
    if (t == 0) {
      float fv = rv[0]; int fg = rg[0]; float fi = rgid[0];
      for (int w = 1; w < 4; ++w) {
        bool better = (rv[w] > fv) || (rv[w] == fv && rgid[w] < fi);
        if (better) { fv = rv[w]; fg = rg[w]; fi = rgid[w]; }
      }
      sval = fv; sgi = fg;
    }
    __syncthreads();
    float best_v = sval; int best_g = sgi;
    if (t == (best_g & 255)) {
      int j = best_g >> 8;
      sbox[0] = bx[j][0]; sbox[1] = bx[j][1]; sbox[2] = bx[j][2]; sbox[3] = bx[j][3];
      scls = cl[j];
    }
    __syncthreads();
    bool valid = best_v > 0.f;
    if (t == 0) {
      int base = n * 100 + it;
      outp[base * 4 + 0] = valid ? sbox[0] : 0.f;
      outp[base * 4 + 1] = valid ? sbox[1] : 0.f;
      outp[base * 4 + 2] = valid ? sbox[2] : 0.f;
      outp[base * 4 + 3] = valid ? sbox[3] : 0.f;
      outp[1600 + base] = valid ? best_v : 0.f;
      outp[2000 + base] = valid ? scls : -1.f;
    }
    float off_ = scls * (2.f * IMG_SIZE);
    float e0 = sbox[0] + off_, e1 = sbox[1] + off_, e2 = sbox[2] + off_, e3 = sbox[3] + off_;
    float a1 = (e2 - e0) * (e3 - e1);
#pragma unroll
    for (int j = 0; j < 20; ++j) {
      float o_ = cl[j] * (2.f * IMG_SIZE);
      float f0 = bx[j][0] + o_, f1 = bx[j][1] + o_, f2 = bx[j][2] + o_, f3 = bx[j][3] + o_;
      float xx1 = fmaxf(e0, f0), yy1 = fmaxf(e1, f1);
      float xx2 = fminf(e2, f2), yy2 = fminf(e3, f3);
      float inter = fmaxf(xx2 - xx1, 0.f) * fmaxf(yy2 - yy1, 0.f);
      float a2 = (f2 - f0) * (f3 - f1);
      float iou = inter / (a1 + a2 - inter + 1e-9f);
      if (iou > 0.6f) sc[j] = -1.f;
      if ((j * 256 + t) == best_g) sc[j] = -1.f;
    }
    __syncthreads();
  }
}

// ==================== host ====================
extern "C" void kernel_launch(void* const* d_in, const int* in_sizes, int n_in,
                              void* d_out, int out_size, void* d_ws, size_t ws_size,
                              hipStream_t stream)
{
  (void)in_sizes; (void)n_in; (void)out_size; (void)ws_size;
  const float* p3 = (const float*)d_in[0];
  const float* p4 = (const float*)d_in[1];
  const float* p5 = (const float*)d_in[2];
  const float* p6 = (const float*)d_in[3];
  const float* p7 = (const float*)d_in[4];
  const float* cls_tw  = (const float*)d_in[5];
  const float* cls_tb  = (const float*)d_in[6];
  const float* bbox_tw = (const float*)d_in[7];
  const float* bbox_tb = (const float*)d_in[8];
  const float* wcls    = (const float*)d_in[9];
  const float* bcls    = (const float*)d_in[10];
  const float* wbox    = (const float*)d_in[11];
  const float* bbox_b  = (const float*)d_in[12];
  const float* wctr    = (const float*)d_in[13];
  const float* bctr    = (const float*)d_in[14];
  const float* scales  = (const float*)d_in[15];
  float* out = (float*)d_out;

  // geometry
  Geo G;
  const int Hs[5] = {100, 50, 25, 13, 7};
  {
    int tpre = 0, ppre = 0, bpre = 0, phw = 0, hw = 0;
    for (int l = 0; l < 5; ++l) {
      int H = Hs[l], W = Hs[l];
      G.Ha[l] = H; G.Wa[l] = W; G.PWa[l] = W + 2; G.PHWa[l] = (H + 2) * (W + 2);
      G.TXa[l] = (W + 15) / 16;
      int TY = (H + 7) / 8;
      G.tp[l] = tpre;  tpre += G.TXa[l] * TY;
      G.pb[l] = ppre;  ppre += (H * W + 63) / 64;
      G.bb[l] = bpre;  bpre += (H * W + 255) / 256;
      G.phwOff[l] = phw; phw += G.PHWa[l];
      G.hwOff[l]  = hw;  hw  += H * W;
    }
    G.tp[5] = tpre; G.pb[5] = ppre; G.bb[5] = bpre;
  }
  const int nTiles = G.tp[5];   // 130
  const int nPrep  = G.pb[5];   // 211
  const int nBoxB  = G.bb[5];   // 55
  const int sumPHW = 14143, sumHW = 13343;

  char* ws = (char*)d_ws;
  size_t off = 0;
  auto alloc = [&](size_t bytes) -> void* {
    off = (off + 255) & ~(size_t)255;
    void* p = ws + off; off += bytes; return p;
  };
  const size_t bufBytes = (size_t)sumPHW * 4 * 256 * 4;
  float* bufA = (float*)alloc(bufBytes);
  float* bufB = (float*)alloc(bufBytes);
  float* bufC = (float*)alloc(bufBytes);
  short* wt   = (short*)alloc((size_t)8 * 3 * 589824 * 2);
  float* score  = (float*)alloc((size_t)sumHW * 4 * 80 * 4);
  float* deltas = (float*)alloc((size_t)sumHW * 4 * 4 * 4);
  float* cbox   = (float*)alloc(4ull * 5000 * 4 * 4);
  float* csc    = (float*)alloc(4ull * 5000 * 4);
  float* ccls   = (float*)alloc(4ull * 5000 * 4);
  float* cgid   = (float*)alloc(4ull * 5000 * 4);
  unsigned* hist = (unsigned*)alloc(20ull * 2048 * 4);
  unsigned* thr  = (unsigned*)alloc(20ull * 8 * 4);

  hipMemsetAsync(bufA, 0, bufBytes, stream);
  hipMemsetAsync(bufB, 0, bufBytes, stream);
  hipMemsetAsync(bufC, 0, bufBytes, stream);
  hipMemsetAsync(cbox, 0, 4ull * 5000 * 4 * 4, stream);
  hipMemsetAsync(csc,  0, 4ull * 5000 * 4, stream);
  hipMemsetAsync(ccls, 0, 4ull * 5000 * 4, stream);
  hipMemsetAsync(cgid, 0, 4ull * 5000 * 4, stream);
  hipMemsetAsync(thr,  0, 20ull * 8 * 4, stream);

  wtrans_k<<<1024, 256, 0, stream>>>(cls_tw, bbox_tw, wt);
  prep_all_k<<<dim3(nPrep, 4), 256, 0, stream>>>(p3, p4, p5, p6, p7, bufC, G);

  const size_t LSTRIDE = 3ull * 589824;  // shorts per conv layer
  dim3 cg(nTiles, 2, 4);
  // cls tower
  conv_all_k<<<cg, 256, 0, stream>>>(bufC, wt + 0 * LSTRIDE, cls_tb + 0 * 256, bufA, G);
  conv_all_k<<<cg, 256, 0, stream>>>(bufA, wt + 1 * LSTRIDE, cls_tb + 1 * 256, bufB, G);
  conv_all_k<<<cg, 256, 0, stream>>>(bufB, wt + 2 * LSTRIDE, cls_tb + 2 * 256, bufA, G);
  conv_all_k<<<cg, 256, 0, stream>>>(bufA, wt + 3 * LSTRIDE, cls_tb + 3 * 256, bufB, G);
  cls_head_k<<<dim3(nPrep, 4), 256, 0, stream>>>(bufB, wcls, bcls, score, G);
  // bbox tower
  conv_all_k<<<cg, 256, 0, stream>>>(bufC, wt + 4 * LSTRIDE, bbox_tb + 0 * 256, bufA, G);
  conv_all_k<<<cg, 256, 0, stream>>>(bufA, wt + 5 * LSTRIDE, bbox_tb + 1 * 256, bufB, G);
  conv_all_k<<<cg, 256, 0, stream>>>(bufB, wt + 6 * LSTRIDE, bbox_tb + 2 * 256, bufA, G);
  conv_all_k<<<cg, 256, 0, stream>>>(bufA, wt + 7 * LSTRIDE, bbox_tb + 3 * 256, bufB, G);
  box_head_k<<<dim3(nBoxB, 4), 256, 0, stream>>>(bufB, wbox, bbox_b, wctr, bctr, scales,
                                                 score, deltas, G);

  // exact top-1000 per (level, image)
  const int hb = 196;
  for (int phase = 0; phase < 3; ++phase) {
    hipMemsetAsync(hist, 0, 20ull * 2048 * 4, stream);
    hist_k<<<dim3(hb, 20), 256, 0, stream>>>(score, thr, hist, phase, G);
    scan_k<<<20, 256, 0, stream>>>(hist, thr, phase);
  }
  select_k<<<dim3(hb, 20), 256, 0, stream>>>(score, deltas, thr, cbox, csc, ccls, cgid, G);

  nms_k<<<4, 256, 0, stream>>>(cbox, csc, ccls, cgid, out);
}

// Round 4
// 3730.688 us; speedup vs baseline: 5.3714x; 1.6112x over previous
//
#include <hip/hip_runtime.h>
#include <math.h>

typedef short s8v __attribute__((ext_vector_type(8)));
typedef float f4v __attribute__((ext_vector_type(4)));

__device__ __forceinline__ float sigf(float x) { return 1.f / (1.f + expf(-x)); }

#define SCALE_CLAMP 4.135166556742356f
#define IMG_SIZE 800.f

// 3-way bf16 split (round-to-nearest): x ~= h + m + l, err ~2^-27 |x|
__device__ __forceinline__ void split3(float x, short& h, short& m, short& l) {
  unsigned u = __float_as_uint(x);
  unsigned hb = (u + 0x7FFFu + ((u >> 16) & 1u)) >> 16;
  float hf = __uint_as_float(hb << 16);
  float d1 = x - hf;
  unsigned u1 = __float_as_uint(d1);
  unsigned mb = (u1 + 0x7FFFu + ((u1 >> 16) & 1u)) >> 16;
  float mf = __uint_as_float(mb << 16);
  float d2 = d1 - mf;
  unsigned u2 = __float_as_uint(d2);
  unsigned lb = (u2 + 0x7FFFu + ((u2 >> 16) & 1u)) >> 16;
  h = (short)hb; m = (short)mb; l = (short)lb;
}

struct Geo {
  int tp[6];                 // conv tile prefix per level
  int TXa[5];
  int Ha[5], Wa[5], PWa[5], PHWa[5];
  int phwOff[5];             // PHW prefix
  int hwOff[5];              // HW prefix
  int pb[6];                 // ceil(HW/64) prefix  (prep + cls head)
  int bb[6];                 // ceil(HW/256) prefix (box head)
};

// ==================== weight split+transpose ====================
// out layout (bf16 shorts): [layer8][plane3][ (tap*8+cc)*4+q ][ko 256][e 8]
// plane stride 589824, layer stride 1769472. ci = cc*32 + q*8 + e.
__global__ __launch_bounds__(256) void wtrans_k(const float* __restrict__ cls_tw,
                                                const float* __restrict__ bbox_tw,
                                                short* __restrict__ wt)
{
  const int total = 589824; // 8 layers * 9 tap * 8 cc * 4 q * 256 ko
  for (int u = blockIdx.x * 256 + threadIdx.x; u < total; u += gridDim.x * 256) {
    int layer = u / 73728;
    int r = u - layer * 73728;
    int tap = r / 8192;  r -= tap * 8192;
    int cc  = r / 1024;  r -= cc * 1024;
    int qq  = r / 256;   int ko = r - qq * 256;
    int cibase = cc * 32 + qq * 8;
    const float* src = (layer < 4) ? (cls_tw + (size_t)layer * 589824)
                                   : (bbox_tw + (size_t)(layer - 4) * 589824);
    s8v hv, mv, lv;
#pragma unroll
    for (int e = 0; e < 8; ++e) {
      float x = src[(size_t)ko * 2304 + (size_t)(cibase + e) * 9 + tap];
      short h, m, l; split3(x, h, m, l);
      hv[e] = h; mv[e] = m; lv[e] = l;
    }
    size_t dbase = (size_t)layer * 1769472 + (((size_t)tap * 8 + cc) * 4 + qq) * 2048 + (size_t)ko * 8;
    *(s8v*)(wt + dbase) = hv;
    *(s8v*)(wt + dbase + 589824) = mv;
    *(s8v*)(wt + dbase + 2 * 589824) = lv;
  }
}

// ==================== NCHW -> padded NHWC fp32 (all levels) ====================
__global__ __launch_bounds__(256) void prep_all_k(const float* __restrict__ p3, const float* __restrict__ p4,
                                                  const float* __restrict__ p5, const float* __restrict__ p6,
                                                  const float* __restrict__ p7,
                                                  float* __restrict__ out, Geo g)
{
  __shared__ float tl[64][260];
  int bx = blockIdx.x, t = threadIdx.x, n = blockIdx.y;
  int l = 0; while (l < 4 && bx >= g.pb[l + 1]) ++l;
  const float* in = (l == 0) ? p3 : (l == 1) ? p4 : (l == 2) ? p5 : (l == 3) ? p6 : p7;
  int H = g.Ha[l], W = g.Wa[l], PW = g.PWa[l], PHW = g.PHWa[l], HW = H * W;
  int P0 = (bx - g.pb[l]) * 64;
  const float* inN = in + (size_t)n * HW * 256;
  int sub = t >> 6, pl = t & 63;
  int pos = P0 + pl;
  for (int i = 0; i < 64; ++i) {
    int ci = i * 4 + sub;
    tl[pl][ci] = (pos < HW) ? inN[(size_t)ci * HW + pos] : 0.f;
  }
  __syncthreads();
  int pl2 = t >> 2, cq = (t & 3) * 64;
  int pos2 = P0 + pl2;
  if (pos2 < HW) {
    int y = pos2 / W, x = pos2 - y * W;
    float* o = out + (((size_t)g.phwOff[l] * 4 + (size_t)n * PHW) + (size_t)(y + 1) * PW + (x + 1)) * 256 + cq;
#pragma unroll
    for (int j = 0; j < 16; ++j) ((float4*)o)[j] = *(const float4*)&tl[pl2][cq + j * 4];
  }
}

// ==================== MFMA conv 3x3 + bias + relu (all levels, one layer) ====================
// Weights: direct global(L2)->reg, double-buffered across the unrolled tap loop.
// act_s only in LDS (34.5 KB); 2 barriers per cc chunk (16 total, was 144).
// Register budget ~233 (acc 64 + bfrA/B 96 + afr 48 + addr) -> no spills at cap 256.
__global__ __launch_bounds__(256, 2) void conv_all_k(const float* __restrict__ in,
                                                     const short* __restrict__ wtL,
                                                     const float* __restrict__ bias,
                                                     float* __restrict__ out, Geo g)
{
  __shared__ short act_s[3 * 720 * 8];  // [plane][q*180+pos][8ci], pos in 10x18 halo

  const int t = threadIdx.x;
  const int lane = t & 63, wave = t >> 6;
  const int wcol = wave & 1, wko = wave >> 1;
  const int n = blockIdx.z;
  const int ko0 = blockIdx.y * 128;
  int bx = blockIdx.x;
  int l = 0; while (l < 4 && bx >= g.tp[l + 1]) ++l;
  const int H = g.Ha[l], W = g.Wa[l], PW = g.PWa[l], PHW = g.PHWa[l];
  const int lt = bx - g.tp[l];
  const int TX = g.TXa[l];
  const int ty = lt / TX, tx = lt - ty * TX;
  const int R0 = ty * 8, C0 = tx * 16;
  const float* inN = in + ((size_t)g.phwOff[l] * 4 + (size_t)n * PHW) * 256;
  float* outN = out + ((size_t)g.phwOff[l] * 4 + (size_t)n * PHW) * 256;

  const int r = lane & 15, q = lane >> 4;
  const int cb = wcol * 8;

  // per-lane weight offset (shorts): q-quarter + ko column
  const short* wlane = wtL + (size_t)q * 2048 + (size_t)(ko0 + wko * 64 + r) * 8;

  f4v acc[4][4];
#pragma unroll
  for (int mi = 0; mi < 4; ++mi)
#pragma unroll
    for (int ni = 0; ni < 4; ++ni) { f4v z = {0.f, 0.f, 0.f, 0.f}; acc[mi][ni] = z; }

  auto stageAct = [&](int cc) {
    for (int j = t; j < 720; j += 256) {
      int qq = j / 180;
      int pos = j - qq * 180;
      int row = pos / 18;
      int col = pos - row * 18;
      int prow = R0 + row; if (prow > H + 1) prow = H + 1;
      int pcol = C0 + col; if (pcol > W + 1) pcol = W + 1;
      const float* gp = inN + ((size_t)prow * PW + pcol) * 256 + cc * 32 + qq * 8;
      float4 v0 = ((const float4*)gp)[0];
      float4 v1 = ((const float4*)gp)[1];
      float xs[8] = {v0.x, v0.y, v0.z, v0.w, v1.x, v1.y, v1.z, v1.w};
      s8v hv, mv, lv;
#pragma unroll
      for (int e = 0; e < 8; ++e) {
        short h, m, lo; split3(xs[e], h, m, lo);
        hv[e] = h; mv[e] = m; lv[e] = lo;
      }
      *(s8v*)&act_s[j * 8] = hv;
      *(s8v*)&act_s[(720 + j) * 8] = mv;
      *(s8v*)&act_s[(1440 + j) * 8] = lv;
    }
  };

  // load one tap's weight fragments (12x16B from L2) into a named buffer
  auto loadB = [&](s8v (&bf)[3][4], int cc2, int tap2) {
    const short* base = wlane + (size_t)(tap2 * 8 + cc2) * 8192;
#pragma unroll
    for (int p = 0; p < 3; ++p)
#pragma unroll
      for (int ni = 0; ni < 4; ++ni)
        bf[p][ni] = *(const s8v*)(base + (size_t)p * 589824 + ni * 128);
  };

  // run one tap: afr LDS loads + 96 MFMAs against the given weight buffer
  auto runTap = [&](const s8v (&bf)[3][4], int dy, int dx) {
    s8v afr[3][4];
#pragma unroll
    for (int mi = 0; mi < 4; ++mi) {
      int sl = q * 180 + (2 * mi + (r >> 3) + dy) * 18 + (cb + (r & 7) + dx);
      afr[0][mi] = *(const s8v*)&act_s[sl * 8];
      afr[1][mi] = *(const s8v*)&act_s[(720 + sl) * 8];
      afr[2][mi] = *(const s8v*)&act_s[(1440 + sl) * 8];
    }
    const int PA[6] = {0, 0, 1, 1, 0, 2};
    const int PB[6] = {0, 1, 0, 1, 2, 0};
#pragma unroll
    for (int pp = 0; pp < 6; ++pp) {
#pragma unroll
      for (int mi = 0; mi < 4; ++mi)
#pragma unroll
        for (int ni = 0; ni < 4; ++ni)
          acc[mi][ni] = __builtin_amdgcn_mfma_f32_16x16x32_bf16(
              afr[PA[pp]][mi], bf[PB[pp]][ni], acc[mi][ni], 0, 0, 0);
    }
  };

  s8v bfrA[3][4], bfrB[3][4];
  loadB(bfrA, 0, 0);  // prologue prefetch

  for (int cc = 0; cc < 8; ++cc) {
    __syncthreads();            // all waves done reading act_s (previous cc)
    stageAct(cc);
    __syncthreads();            // staging visible
#pragma unroll
    for (int tap = 0; tap < 9; ++tap) {
      const int dy = tap / 3, dx = tap - dy * 3;
      // prefetch next tap's weights into the other buffer
      if (tap < 8) {
        if (tap & 1) loadB(bfrA, cc, tap + 1); else loadB(bfrB, cc, tap + 1);
      } else if (cc < 7) {
        loadB(bfrB, cc + 1, 0);  // tap==8 is even -> next uses B
      }
      if (tap & 1) runTap(bfrB, dy, dx); else runTap(bfrA, dy, dx);
      // parity: after tap 8 (even, used A), next cc's tap 0 uses... tap0 even -> A.
      // So copy B->A at cc boundary is avoided by loading into B above and
      // swapping: handle by loading cc+1 tap0 into bfrA instead:
    }
    // fix-up: the cc-boundary prefetch above went to bfrB, but tap0 reads bfrA.
    if (cc < 7) {
#pragma unroll
      for (int p = 0; p < 3; ++p)
#pragma unroll
        for (int ni = 0; ni < 4; ++ni) bfrA[p][ni] = bfrB[p][ni];
    }
  }

  // epilogue: bias + relu, masked store
#pragma unroll
  for (int mi = 0; mi < 4; ++mi) {
#pragma unroll
    for (int ni = 0; ni < 4; ++ni) {
      int ko = ko0 + wko * 64 + ni * 16 + r;
      float bv = bias[ko];
#pragma unroll
      for (int reg = 0; reg < 4; ++reg) {
        int rm = q * 4 + reg;
        int orow = R0 + 2 * mi + (rm >> 3);
        int ocol = C0 + cb + (rm & 7);
        if (orow < H && ocol < W) {
          float vv = acc[mi][ni][reg] + bv;
          outN[((size_t)(orow + 1) * PW + (ocol + 1)) * 256 + ko] = fmaxf(vv, 0.f);
        }
      }
    }
  }
}

// ==================== cls head (all levels): 1x1x80 + sigmoid ====================
__global__ __launch_bounds__(256) void cls_head_k(const float* __restrict__ act,
                                                  const float* __restrict__ wcls,
                                                  const float* __restrict__ bcls,
                                                  float* __restrict__ score, Geo g)
{
  __shared__ int   p2s[64];
  __shared__ float as_[64][69];
  __shared__ float ws_[64][84];
  const int t = threadIdx.x;
  const int n = blockIdx.y;
  int bx = blockIdx.x;
  int l = 0; while (l < 4 && bx >= g.pb[l + 1]) ++l;
  const int H = g.Ha[l], W = g.Wa[l], PW = g.PWa[l], PHW = g.PHWa[l], HW = H * W;
  const int P0 = (bx - g.pb[l]) * 64;
  if (t < 64) {
    int p = P0 + t; if (p >= HW) p = HW - 1;
    int y = p / W, x = p - y * W;
    p2s[t] = (y + 1) * PW + x + 1;
  }
  __syncthreads();
  float accv[4][5];
#pragma unroll
  for (int i = 0; i < 4; ++i)
#pragma unroll
    for (int j = 0; j < 5; ++j) accv[i][j] = 0.f;

  const float* actN = act + ((size_t)g.phwOff[l] * 4 + (size_t)n * PHW) * 256;
  const int pg = t >> 4, cg = t & 15;

  for (int c0 = 0; c0 < 256; c0 += 64) {
    for (int i = t; i < 1024; i += 256) {
      int pos = i >> 4, c4 = i & 15;
      float4 v = *(const float4*)(actN + (size_t)p2s[pos] * 256 + c0 + c4 * 4);
      float* dst = &as_[pos][c4 * 4];
      dst[0] = v.x; dst[1] = v.y; dst[2] = v.z; dst[3] = v.w;
    }
    for (int i = t; i < 1280; i += 256) {
      int c = i >> 4, c4 = i & 15;
      float4 v = *(const float4*)(wcls + (size_t)c * 256 + c0 + c4 * 4);
      ws_[c4 * 4 + 0][c] = v.x; ws_[c4 * 4 + 1][c] = v.y;
      ws_[c4 * 4 + 2][c] = v.z; ws_[c4 * 4 + 3][c] = v.w;
    }
    __syncthreads();
#pragma unroll 8
    for (int ci = 0; ci < 64; ++ci) {
#pragma unroll
      for (int i = 0; i < 4; ++i) {
        float a = as_[pg * 4 + i][ci];
#pragma unroll
        for (int j = 0; j < 5; ++j)
          accv[i][j] = fmaf(a, ws_[ci][cg * 5 + j], accv[i][j]);
      }
    }
    __syncthreads();
  }
  float* sB = score + ((size_t)g.hwOff[l] * 4 + (size_t)n * HW) * 80;
#pragma unroll
  for (int i = 0; i < 4; ++i) {
    int p = P0 + pg * 4 + i;
    if (p >= HW) continue;
#pragma unroll
    for (int j = 0; j < 5; ++j) {
      int c = cg * 5 + j;
      sB[(size_t)p * 80 + c] = sigf(accv[i][j] + bcls[c]);
    }
  }
}

// ==================== box head (all levels) ====================
__global__ __launch_bounds__(256) void box_head_k(const float* __restrict__ act,
                                                  const float* __restrict__ wbox,
                                                  const float* __restrict__ bb,
                                                  const float* __restrict__ wctr,
                                                  const float* __restrict__ bc,
                                                  const float* __restrict__ scales,
                                                  float* __restrict__ score,
                                                  float* __restrict__ deltas, Geo g)
{
  int n = blockIdx.y;
  int bx = blockIdx.x;
  int l = 0; while (l < 4 && bx >= g.bb[l + 1]) ++l;
  const int H = g.Ha[l], W = g.Wa[l], PW = g.PWa[l], PHW = g.PHWa[l], HW = H * W;
  int p = (bx - g.bb[l]) * 256 + threadIdx.x;
  if (p >= HW) return;
  int y = p / W, x = p - y * W;
  const float* a = act + (((size_t)g.phwOff[l] * 4 + (size_t)n * PHW) + (size_t)(y + 1) * PW + x + 1) * 256;
  float d0 = 0, d1 = 0, d2 = 0, d3 = 0, ct = 0;
  for (int i = 0; i < 64; ++i) {
    float4 av = ((const float4*)a)[i];
    float4 w0 = ((const float4*)wbox)[0 * 64 + i];
    float4 w1 = ((const float4*)wbox)[1 * 64 + i];
    float4 w2 = ((const float4*)wbox)[2 * 64 + i];
    float4 w3 = ((const float4*)wbox)[3 * 64 + i];
    float4 wc = ((const float4*)wctr)[i];
    d0 = fmaf(av.x, w0.x, d0); d0 = fmaf(av.y, w0.y, d0); d0 = fmaf(av.z, w0.z, d0); d0 = fmaf(av.w, w0.w, d0);
    d1 = fmaf(av.x, w1.x, d1); d1 = fmaf(av.y, w1.y, d1); d1 = fmaf(av.z, w1.z, d1); d1 = fmaf(av.w, w1.w, d1);
    d2 = fmaf(av.x, w2.x, d2); d2 = fmaf(av.y, w2.y, d2); d2 = fmaf(av.z, w2.z, d2); d2 = fmaf(av.w, w2.w, d2);
    d3 = fmaf(av.x, w3.x, d3); d3 = fmaf(av.y, w3.y, d3); d3 = fmaf(av.z, w3.z, d3); d3 = fmaf(av.w, w3.w, d3);
    ct = fmaf(av.x, wc.x, ct); ct = fmaf(av.y, wc.y, ct); ct = fmaf(av.z, wc.z, ct); ct = fmaf(av.w, wc.w, ct);
  }
  float sl = scales[l];
  float* dd = deltas + ((size_t)g.hwOff[l] * 4 + (size_t)n * HW + p) * 4;
  dd[0] = sl * (d0 + bb[0]); dd[1] = sl * (d1 + bb[1]);
  dd[2] = sl * (d2 + bb[2]); dd[3] = sl * (d3 + bb[3]);
  float sct = sigf(ct + bc[0]);
  float* sp = score + ((size_t)g.hwOff[l] * 4 + (size_t)n * HW + p) * 80;
#pragma unroll
  for (int i = 0; i < 20; ++i) {
    float4 v = ((float4*)sp)[i];
    v.x *= sct; v.y *= sct; v.z *= sct; v.w *= sct;
    v.x = (v.x > 0.05f) ? v.x : 0.f;
    v.y = (v.y > 0.05f) ? v.y : 0.f;
    v.z = (v.z > 0.05f) ? v.z : 0.f;
    v.w = (v.w > 0.05f) ? v.w : 0.f;
    ((float4*)sp)[i] = v;
  }
}

// ==================== exact top-1000: 3-pass bit histogram over 20 (level,image) groups ====================
__global__ __launch_bounds__(256) void hist_k(const float* __restrict__ score,
                                              const unsigned* __restrict__ thr,
                                              unsigned* __restrict__ hist, int phase, Geo g)
{
  const int grp = blockIdx.y;
  const int l = grp >> 2, n = grp & 3;
  const int HW = g.Ha[l] * g.Wa[l];
  const int M = HW * 80;
  const float* s = score + ((size_t)g.hwOff[l] * 4 + (size_t)n * HW) * 80;
  unsigned* h = hist + grp * 2048;
  const unsigned* tr = thr + grp * 8;
  __shared__ unsigned lh[2048];
  for (int i = threadIdx.x; i < 2048; i += 256) lh[i] = 0u;
  __syncthreads();
  unsigned B1 = 0, pref = 0;
  if (phase == 1) B1 = tr[0];
  if (phase == 2) pref = (tr[0] << 11) | tr[1];
  for (int idx = blockIdx.x * 256 + threadIdx.x; idx < M; idx += gridDim.x * 256) {
    float v = s[idx];
    if (v > 0.f) {
      unsigned b = __float_as_uint(v);
      if (phase == 0) atomicAdd(&lh[b >> 20], 1u);
      else if (phase == 1) { if ((b >> 20) == B1) atomicAdd(&lh[(b >> 9) & 0x7FFu], 1u); }
      else { if ((b >> 9) == pref) atomicAdd(&lh[b & 0x1FFu], 1u); }
    }
  }
  __syncthreads();
  for (int i = threadIdx.x; i < 2048; i += 256) { unsigned v = lh[i]; if (v) atomicAdd(&h[i], v); }
}

__global__ __launch_bounds__(256) void scan_k(unsigned* __restrict__ hist,
                                              unsigned* __restrict__ thr, int phase)
{
  const int grp = blockIdx.x, t = threadIdx.x;
  unsigned* h  = hist + grp * 2048;
  unsigned* tr = thr + grp * 8;
  const int nb = (phase == 2) ? 512 : 2048;
  const int PB = nb / 256;
  unsigned target = 1000u;
  bool dead = false;
  if (phase >= 1) {
    target = 1000u - tr[2];
    if (tr[0] == 0xFFFFFFFFu) dead = true;
    if (phase == 2 && tr[1] == 0xFFFFFFFFu) dead = true;
  }
  __shared__ unsigned ps[256];
  __shared__ unsigned s_tot;
  const int hi = nb - t * PB;
  unsigned lsum = 0;
  for (int k = 0; k < PB; ++k) lsum += h[hi - 1 - k];
  ps[t] = lsum;
  __syncthreads();
  if (t == 0) {
    unsigned cum = 0;
    for (int i = 0; i < 256; ++i) { unsigned tmp = ps[i]; ps[i] = cum; cum += tmp; }
    s_tot = cum;
  }
  __syncthreads();
  unsigned exc = ps[t], tot = s_tot;
  if (!dead && tot >= target) {
    if (exc < target && exc + lsum >= target) {
      unsigned cum = exc; int bf = 0; unsigned above = 0;
      for (int k = 0; k < PB; ++k) {
        int bidx = hi - 1 - k;
        unsigned c = h[bidx];
        if (cum < target && cum + c >= target) { bf = bidx; above = cum; }
        cum += c;
      }
      if (phase == 0)      { tr[0] = (unsigned)bf; tr[2] = above; }
      else if (phase == 1) { tr[1] = (unsigned)bf; tr[2] = tr[2] + above; }
      else {
        unsigned T = (tr[0] << 20) | (tr[1] << 9) | (unsigned)bf;
        tr[3] = T; tr[4] = target - above;
      }
    }
  } else if (t == 0) {
    if (phase == 0)      { tr[0] = 0xFFFFFFFFu; tr[2] = 0u; }
    else if (phase == 1) { tr[1] = 0xFFFFFFFFu; }
    else                 { tr[3] = 0u; tr[4] = 0u; }
  }
  if (phase == 2 && t == 0) { tr[5] = 0u; tr[6] = 0u; }
}

// ==================== select + decode ====================
__global__ __launch_bounds__(256) void select_k(const float* __restrict__ score,
                                                const float* __restrict__ deltas,
                                                unsigned* __restrict__ thr,
                                                float* __restrict__ cbox, float* __restrict__ csc,
                                                float* __restrict__ ccls, float* __restrict__ cgid,
                                                Geo g)
{
  const int grp = blockIdx.y;
  const int l = grp >> 2, n = grp & 3;
  const int W = g.Wa[l];
  const int HW = g.Ha[l] * W;
  const int M = HW * 80;
  const float stride_ = (float)(8 << l);
  const float* s = score + ((size_t)g.hwOff[l] * 4 + (size_t)n * HW) * 80;
  const float* dBase = deltas + ((size_t)g.hwOff[l] * 4 + (size_t)n * HW) * 4;
  unsigned* tr = thr + grp * 8;
  const unsigned T = tr[3], need = tr[4];
  for (int idx = blockIdx.x * 256 + threadIdx.x; idx < M; idx += gridDim.x * 256) {
    float v = s[idx];
    if (!(v > 0.f)) continue;
    unsigned b = __float_as_uint(v);
    int slot = -1;
    if (b > T) slot = (int)atomicAdd(&tr[5], 1u);
    else if (b == T) {
      unsigned e = atomicAdd(&tr[6], 1u);
      if (e < need) slot = (int)(1000u - need + e);
    }
    if (slot < 0) continue;
    int p = idx / 80, c = idx - p * 80;
    int y = p / W, x = p - y * W;
    const float* d = dBase + (size_t)p * 4;
    float sz  = 8.f * stride_;
    float acx = ((float)x + 0.5f) * stride_;
    float acy = ((float)y + 0.5f) * stride_;
    float dx = d[0] / 10.f, dy = d[1] / 10.f;
    float dw = fminf(d[2] / 5.f, SCALE_CLAMP);
    float dh = fminf(d[3] / 5.f, SCALE_CLAMP);
    float pcx = dx * sz + acx;
    float pcy = dy * sz + acy;
    float pw = expf(dw) * sz;
    float ph = expf(dh) * sz;
    float x1 = pcx - 0.5f * pw, y1_ = pcy - 0.5f * ph;
    float x2 = pcx + 0.5f * pw, y2_ = pcy + 0.5f * ph;
    x1  = fminf(fmaxf(x1, 0.f),  IMG_SIZE);
    y1_ = fminf(fmaxf(y1_, 0.f), IMG_SIZE);
    x2  = fminf(fmaxf(x2, 0.f),  IMG_SIZE);
    y2_ = fminf(fmaxf(y2_, 0.f), IMG_SIZE);
    int cslot = n * 5000 + l * 1000 + slot;
    ((float4*)cbox)[cslot] = make_float4(x1, y1_, x2, y2_);
    csc[cslot]  = sqrtf(v);
    ccls[cslot] = (float)c;
    cgid[cslot] = (float)(((unsigned)l << 20) | (unsigned)idx);
  }
}

// ==================== class-aware greedy NMS ====================
__global__ __launch_bounds__(256) void nms_k(const float* __restrict__ cbox,
                                             const float* __restrict__ csc,
                                             const float* __restrict__ ccls,
                                             const float* __restrict__ cgid,
                                             float* __restrict__ outp)
{
  const int n = blockIdx.x, t = threadIdx.x;
  float sc[20], cl[20], gid[20], bx[20][4];
#pragma unroll
  for (int j = 0; j < 20; ++j) {
    int gidx = j * 256 + t;
    if (gidx < 5000) {
      sc[j] = csc[n * 5000 + gidx];
      float4 b = ((const float4*)cbox)[n * 5000 + gidx];
      bx[j][0] = b.x; bx[j][1] = b.y; bx[j][2] = b.z; bx[j][3] = b.w;
      cl[j]  = ccls[n * 5000 + gidx];
      gid[j] = cgid[n * 5000 + gidx];
    } else { sc[j] = -2.f; bx[j][0] = bx[j][1] = bx[j][2] = bx[j][3] = 0.f; cl[j] = 0.f; gid[j] = 1e9f; }
  }
  __shared__ float rv[4]; __shared__ int rg[4]; __shared__ float rgid[4];
  __shared__ float sbox[4]; __shared__ float scls; __shared__ float sval; __shared__ int sgi;

  for (int it = 0; it < 100; ++it) {
    float bv = -3.f; int bg = 0; float bgid = 2e9f;
#pragma unroll
    for (int j = 0; j < 20; ++j) {
      bool better = (sc[j] > bv) || (sc[j] == bv && gid[j] < bgid);
      if (better) { bv = sc[j]; bg = j * 256 + t; bgid = gid[j]; }
    }
    for (int off = 32; off; off >>= 1) {
      float ov = __shfl_xor(bv, off);
      int   og = __shfl_xor(bg, off);
      float oi = __shfl_xor(bgid, off);
      bool better = (ov > bv) || (ov == bv && oi < bgid);
      if (better) { bv = ov; bg = og; bgid = oi; }
    }
    int wid = t >> 6;
    if ((t & 63) == 0) { rv[wid] = bv; rg[wid] = bg; rgid[wid] = bgid; }
    __syncthreads();
    if (t == 0) {
      float fv = rv[0]; int fg = rg[0]; float fi = rgid[0];
      for (int w = 1; w < 4; ++w) {
        bool better = (rv[w] > fv) || (rv[w] == fv && rgid[w] < fi);
        if (better) { fv = rv[w]; fg = rg[w]; fi = rgid[w]; }
      }
      sval = fv; sgi = fg;
    }
    __syncthreads();
    float best_v = sval; int best_g = sgi;
    if (t == (best_g & 255)) {
      int j = best_g >> 8;
      sbox[0] = bx[j][0]; sbox[1] = bx[j][1]; sbox[2] = bx[j][2]; sbox[3] = bx[j][3];
      scls = cl[j];
    }
    __syncthreads();
    bool valid = best_v > 0.f;
    if (t == 0) {
      int base = n * 100 + it;
      outp[base * 4 + 0] = valid ? sbox[0] : 0.f;
      outp[base * 4 + 1] = valid ? sbox[1] : 0.f;
      outp[base * 4 + 2] = valid ? sbox[2] : 0.f;
      outp[base * 4 + 3] = valid ? sbox[3] : 0.f;
      outp[1600 + base] = valid ? best_v : 0.f;
      outp[2000 + base] = valid ? scls : -1.f;
    }
    float off_ = scls * (2.f * IMG_SIZE);
    float e0 = sbox[0] + off_, e1 = sbox[1] + off_, e2 = sbox[2] + off_, e3 = sbox[3] + off_;
    float a1 = (e2 - e0) * (e3 - e1);
#pragma unroll
    for (int j = 0; j < 20; ++j) {
      float o_ = cl[j] * (2.f * IMG_SIZE);
      float f0 = bx[j][0] + o_, f1 = bx[j][1] + o_, f2 = bx[j][2] + o_, f3 = bx[j][3] + o_;
      float xx1 = fmaxf(e0, f0), yy1 = fmaxf(e1, f1);
      float xx2 = fminf(e2, f2), yy2 = fminf(e3, f3);
      float inter = fmaxf(xx2 - xx1, 0.f) * fmaxf(yy2 - yy1, 0.f);
      float a2 = (f2 - f0) * (f3 - f1);
      float iou = inter / (a1 + a2 - inter + 1e-9f);
      if (iou > 0.6f) sc[j] = -1.f;
      if ((j * 256 + t) == best_g) sc[j] = -1.f;
    }
    __syncthreads();
  }
}

// ==================== host ====================
extern "C" void kernel_launch(void* const* d_in, const int* in_sizes, int n_in,
                              void* d_out, int out_size, void* d_ws, size_t ws_size,
                              hipStream_t stream)
{
  (void)in_sizes; (void)n_in; (void)out_size; (void)ws_size;
  const float* p3 = (const float*)d_in[0];
  const float* p4 = (const float*)d_in[1];
  const float* p5 = (const float*)d_in[2];
  const float* p6 = (const float*)d_in[3];
  const float* p7 = (const float*)d_in[4];
  const float* cls_tw  = (const float*)d_in[5];
  const float* cls_tb  = (const float*)d_in[6];
  const float* bbox_tw = (const float*)d_in[7];
  const float* bbox_tb = (const float*)d_in[8];
  const float* wcls    = (const float*)d_in[9];
  const float* bcls    = (const float*)d_in[10];
  const float* wbox    = (const float*)d_in[11];
  const float* bbox_b  = (const float*)d_in[12];
  const float* wctr    = (const float*)d_in[13];
  const float* bctr    = (const float*)d_in[14];
  const float* scales  = (const float*)d_in[15];
  float* out = (float*)d_out;

  // geometry
  Geo G;
  const int Hs[5] = {100, 50, 25, 13, 7};
  {
    int tpre = 0, ppre = 0, bpre = 0, phw = 0, hw = 0;
    for (int l = 0; l < 5; ++l) {
      int H = Hs[l], W = Hs[l];
      G.Ha[l] = H; G.Wa[l] = W; G.PWa[l] = W + 2; G.PHWa[l] = (H + 2) * (W + 2);
      G.TXa[l] = (W + 15) / 16;
      int TY = (H + 7) / 8;
      G.tp[l] = tpre;  tpre += G.TXa[l] * TY;
      G.pb[l] = ppre;  ppre += (H * W + 63) / 64;
      G.bb[l] = bpre;  bpre += (H * W + 255) / 256;
      G.phwOff[l] = phw; phw += G.PHWa[l];
      G.hwOff[l]  = hw;  hw  += H * W;
    }
    G.tp[5] = tpre; G.pb[5] = ppre; G.bb[5] = bpre;
  }
  const int nTiles = G.tp[5];   // 130
  const int nPrep  = G.pb[5];   // 211
  const int nBoxB  = G.bb[5];   // 55
  const int sumPHW = 14143, sumHW = 13343;

  char* ws = (char*)d_ws;
  size_t off = 0;
  auto alloc = [&](size_t bytes) -> void* {
    off = (off + 255) & ~(size_t)255;
    void* p = ws + off; off += bytes; return p;
  };
  const size_t bufBytes = (size_t)sumPHW * 4 * 256 * 4;
  float* bufA = (float*)alloc(bufBytes);
  float* bufB = (float*)alloc(bufBytes);
  float* bufC = (float*)alloc(bufBytes);
  short* wt   = (short*)alloc((size_t)8 * 3 * 589824 * 2);
  float* score  = (float*)alloc((size_t)sumHW * 4 * 80 * 4);
  float* deltas = (float*)alloc((size_t)sumHW * 4 * 4 * 4);
  float* cbox   = (float*)alloc(4ull * 5000 * 4 * 4);
  float* csc    = (float*)alloc(4ull * 5000 * 4);
  float* ccls   = (float*)alloc(4ull * 5000 * 4);
  float* cgid   = (float*)alloc(4ull * 5000 * 4);
  unsigned* hist = (unsigned*)alloc(20ull * 2048 * 4);
  unsigned* thr  = (unsigned*)alloc(20ull * 8 * 4);

  hipMemsetAsync(bufA, 0, bufBytes, stream);
  hipMemsetAsync(bufB, 0, bufBytes, stream);
  hipMemsetAsync(bufC, 0, bufBytes, stream);
  hipMemsetAsync(cbox, 0, 4ull * 5000 * 4 * 4, stream);
  hipMemsetAsync(csc,  0, 4ull * 5000 * 4, stream);
  hipMemsetAsync(ccls, 0, 4ull * 5000 * 4, stream);
  hipMemsetAsync(cgid, 0, 4ull * 5000 * 4, stream);
  hipMemsetAsync(thr,  0, 20ull * 8 * 4, stream);

  wtrans_k<<<1024, 256, 0, stream>>>(cls_tw, bbox_tw, wt);
  prep_all_k<<<dim3(nPrep, 4), 256, 0, stream>>>(p3, p4, p5, p6, p7, bufC, G);

  const size_t LSTRIDE = 3ull * 589824;  // shorts per conv layer
  dim3 cg(nTiles, 2, 4);
  // cls tower
  conv_all_k<<<cg, 256, 0, stream>>>(bufC, wt + 0 * LSTRIDE, cls_tb + 0 * 256, bufA, G);
  conv_all_k<<<cg, 256, 0, stream>>>(bufA, wt + 1 * LSTRIDE, cls_tb + 1 * 256, bufB, G);
  conv_all_k<<<cg, 256, 0, stream>>>(bufB, wt + 2 * LSTRIDE, cls_tb + 2 * 256, bufA, G);
  conv_all_k<<<cg, 256, 0, stream>>>(bufA, wt + 3 * LSTRIDE, cls_tb + 3 * 256, bufB, G);
  cls_head_k<<<dim3(nPrep, 4), 256, 0, stream>>>(bufB, wcls, bcls, score, G);
  // bbox tower
  conv_all_k<<<cg, 256, 0, stream>>>(bufC, wt + 4 * LSTRIDE, bbox_tb + 0 * 256, bufA, G);
  conv_all_k<<<cg, 256, 0, stream>>>(bufA, wt + 5 * LSTRIDE, bbox_tb + 1 * 256, bufB, G);
  conv_all_k<<<cg, 256, 0, stream>>>(bufB, wt + 6 * LSTRIDE, bbox_tb + 2 * 256, bufA, G);
  conv_all_k<<<cg, 256, 0, stream>>>(bufA, wt + 7 * LSTRIDE, bbox_tb + 3 * 256, bufB, G);
  box_head_k<<<dim3(nBoxB, 4), 256, 0, stream>>>(bufB, wbox, bbox_b, wctr, bctr, scales,
                                                 score, deltas, G);

  // exact top-1000 per (level, image)
  const int hb = 196;
  for (int phase = 0; phase < 3; ++phase) {
    hipMemsetAsync(hist, 0, 20ull * 2048 * 4, stream);
    hist_k<<<dim3(hb, 20), 256, 0, stream>>>(score, thr, hist, phase, G);
    scan_k<<<20, 256, 0, stream>>>(hist, thr, phase);
  }
  select_k<<<dim3(hb, 20), 256, 0, stream>>>(score, deltas, thr, cbox, csc, ccls, cgid, G);

  nms_k<<<4, 256, 0, stream>>>(cbox, csc, ccls, cgid, out);
}